// Round 7
// baseline (485.418 us; speedup 1.0000x reference)
//
#include <hip/hip_runtime.h>
#include <math.h>

#define HIDN 128
#define EPS 1e-5f
#define ATT_SCALE 0.17677669529663687f   // 32^-0.5

typedef unsigned int  u32;
typedef unsigned short u16;
typedef __attribute__((ext_vector_type(8))) short bf16x8;   // 8 bf16 in 4 VGPRs
typedef __attribute__((ext_vector_type(4))) float f32x4;

__device__ __forceinline__ u16 f2b(float x) {           // fp32 -> bf16 RNE
    u32 u = __float_as_uint(x);
    u += 0x7FFFu + ((u >> 16) & 1u);
    return (u16)(u >> 16);
}
__device__ __forceinline__ float b2f(u16 x) { return __uint_as_float(((u32)x) << 16); }

#define MFMA(a, b, c) __builtin_amdgcn_mfma_f32_16x16x32_bf16((a), (b), (c), 0, 0, 0)

// XOR-swizzled LDS index (u16 elements, 16B granules, stride = u16 per row).
// Same function used on write and read sides (involution).
__device__ __forceinline__ int swz(int row, int kpos, int rowstride) {
    return row * rowstride + ((((kpos >> 3) ^ (row & 7)) << 3) | (kpos & 7));
}
// f32 variant ([16][128] f32, 16B granule = 4 floats)
__device__ __forceinline__ int swzf(int row, int kpos) {
    return row * 128 + ((((kpos >> 2) ^ (row & 7)) << 2) | (kpos & 3));
}

// ---------------------------------------------------------------------------
// Pack all 6 weight matrices (fp32 row-major [K][N]) into MFMA B-fragment
// order, bf16.  Fragment fi = t*KC + c; lane l; elem j -> W[c*32+(l>>4)*8+j][t*16+(l&15)]
// ---------------------------------------------------------------------------
__global__ __launch_bounds__(256) void k_pack_all(
    const float* __restrict__ Wq, const float* __restrict__ Wk, const float* __restrict__ Wv,
    const float* __restrict__ Wo, const float* __restrict__ W1, const float* __restrict__ W2,
    u16* __restrict__ out)
{
    int idx = blockIdx.x * 256 + threadIdx.x;
    const float* W; int K, N, base, local;
    if      (idx <  2048) { W = Wq; K = 128; N = 128; base = 0;     local = idx; }
    else if (idx <  4096) { W = Wk; K = 128; N = 128; base = 16384; local = idx - 2048; }
    else if (idx <  6144) { W = Wv; K = 128; N = 128; base = 32768; local = idx - 4096; }
    else if (idx <  8192) { W = Wo; K = 128; N = 128; base = 49152; local = idx - 6144; }
    else if (idx < 12288) { W = W1; K = 128; N = 256; base = 65536; local = idx - 8192; }
    else if (idx < 16384) { W = W2; K = 256; N = 128; base = 98304; local = idx - 12288; }
    else return;
    const int KC = K >> 5;
    const int l  = local & 63;
    const int tc = local >> 6;
    const int c  = tc % KC;
    const int t  = tc / KC;
    const int col = l & 15, hg = l >> 4;
    const int kbase = c * 32 + hg * 8;
    u16 v[8];
    #pragma unroll
    for (int j = 0; j < 8; ++j) v[j] = f2b(W[(size_t)(kbase + j) * N + t * 16 + col]);
    uint4 o;
    o.x = (u32)v[0] | ((u32)v[1] << 16);
    o.y = (u32)v[2] | ((u32)v[3] << 16);
    o.z = (u32)v[4] | ((u32)v[5] << 16);
    o.w = (u32)v[6] | ((u32)v[7] << 16);
    *(uint4*)&out[base + local * 8] = o;
}

// ---------------------------------------------------------------------------
// QKV fused with LN1: per wave 16 rows; A loaded fp32 from h, LN in-register
// (4-lane shfl reduce), packed to bf16 frags; 3 GEMMs; outputs transposed via
// per-wave LDS to 16B coalesced stores.
// ---------------------------------------------------------------------------
__global__ __launch_bounds__(256) void k_qkv(
    const float* __restrict__ h, const float* __restrict__ g1, const float* __restrict__ be1,
    const u16* __restrict__ Bq, const u16* __restrict__ Bk, const u16* __restrict__ Bv,
    const float* __restrict__ bq, const float* __restrict__ bk, const float* __restrict__ bv,
    u16* __restrict__ Q, u16* __restrict__ K, u16* __restrict__ V, int M)
{
    __shared__ u16 smem[4][2048];                 // 4 KB per wave: [16][128] bf16
    const int wid = threadIdx.x >> 6;
    const int l   = threadIdx.x & 63;
    int slab = blockIdx.x * 4 + wid;
    const bool valid = (slab * 16) < M;
    if (!valid) slab = 0;                         // safe loads; stores predicated
    const int r0  = slab * 16;
    const int col = l & 15, hg = l >> 4;
    u16* ws = smem[wid];

    // ---- load 32 fp32 of my row, LN stats ----
    float av[4][8];
    const float* hr = h + (size_t)(r0 + col) * 128 + hg * 8;
    #pragma unroll
    for (int c = 0; c < 4; ++c) {
        float4 p0 = *(const float4*)&hr[c * 32];
        float4 p1 = *(const float4*)&hr[c * 32 + 4];
        av[c][0] = p0.x; av[c][1] = p0.y; av[c][2] = p0.z; av[c][3] = p0.w;
        av[c][4] = p1.x; av[c][5] = p1.y; av[c][6] = p1.z; av[c][7] = p1.w;
    }
    float s = 0.f, q2 = 0.f;
    #pragma unroll
    for (int c = 0; c < 4; ++c)
        #pragma unroll
        for (int j = 0; j < 8; ++j) { float v = av[c][j]; s += v; q2 += v * v; }
    s  += __shfl_xor(s, 16);  s  += __shfl_xor(s, 32);
    q2 += __shfl_xor(q2, 16); q2 += __shfl_xor(q2, 32);
    float mean = s * (1.f / 128.f);
    float var  = q2 * (1.f / 128.f) - mean * mean;
    float rs   = rsqrtf(var + EPS);

    // ---- normalize, scale, pack to bf16 A-frags ----
    bf16x8 af[4];
    #pragma unroll
    for (int c = 0; c < 4; ++c) {
        u32 w[4];
        #pragma unroll
        for (int jj = 0; jj < 4; ++jj) {
            int k0 = c * 32 + hg * 8 + 2 * jj;
            float v0 = (av[c][2 * jj]     - mean) * rs * g1[k0]     + be1[k0];
            float v1 = (av[c][2 * jj + 1] - mean) * rs * g1[k0 + 1] + be1[k0 + 1];
            w[jj] = (u32)f2b(v0) | ((u32)f2b(v1) << 16);
        }
        uint4 uu = make_uint4(w[0], w[1], w[2], w[3]);
        af[c] = *(bf16x8*)&uu;
    }

    // ---- 3 GEMMs with LDS-transposed vector stores ----
    const u16*  Bs[3] = {Bq, Bk, Bv};
    const float* bs[3] = {bq, bk, bv};
    u16*        Os[3] = {Q, K, V};
    #pragma unroll
    for (int w = 0; w < 3; ++w) {
        const u16* Bp = Bs[w];
        const float* bias = bs[w];
        #pragma unroll
        for (int t = 0; t < 8; ++t) {
            float bb = bias[t * 16 + col];
            f32x4 c = {bb, bb, bb, bb};
            const u16* bp = Bp + t * 2048 + l * 8;
            c = MFMA(af[0], *(const bf16x8*)(bp),        c);
            c = MFMA(af[1], *(const bf16x8*)(bp + 512),  c);
            c = MFMA(af[2], *(const bf16x8*)(bp + 1024), c);
            c = MFMA(af[3], *(const bf16x8*)(bp + 1536), c);
            #pragma unroll
            for (int r = 0; r < 4; ++r)
                ws[swz(hg * 4 + r, t * 16 + col, 128)] = f2b(c[r]);
        }
        __syncthreads();
        if (valid) {
            u16* O = Os[w];
            #pragma unroll
            for (int i = 0; i < 4; ++i) {
                int row = i * 4 + (l >> 4);
                int cg  = l & 15;
                bf16x8 vv = *(const bf16x8*)&ws[swz(row, cg * 8, 128)];
                *(bf16x8*)&O[(size_t)(r0 + row) * 128 + cg * 8] = vv;
            }
        }
        __syncthreads();                          // WAR before next output reuses ws
    }
}

// ---------------------------------------------------------------------------
// CSR build, two-level (bucket = 256 consecutive dst nodes).
// ---------------------------------------------------------------------------
#define BSH 8
#define CHUNK 4096

__global__ __launch_bounds__(256) void k_bcount(
    const int* __restrict__ dst, int* __restrict__ bcnt, int e)
{
    __shared__ int hist[512];
    const int tid = threadIdx.x;
    hist[tid] = 0; hist[tid + 256] = 0;
    __syncthreads();
    const int i0 = blockIdx.x * CHUNK;
    #pragma unroll
    for (int t = 0; t < CHUNK / 256; ++t) {
        int i = i0 + t * 256 + tid;
        if (i < e) atomicAdd(&hist[dst[i] >> BSH], 1);
    }
    __syncthreads();
    for (int j = tid; j < 512; j += 256) {
        int c = hist[j];
        if (c) atomicAdd(&bcnt[j], c);
    }
}

__global__ __launch_bounds__(512) void k_bscan(
    const int* __restrict__ bcnt, int* __restrict__ bbase, int* __restrict__ bcur, int nbuck)
{
    __shared__ int ts[512];
    const int tid = threadIdx.x;
    int v = (tid < nbuck) ? bcnt[tid] : 0;
    ts[tid] = v;
    __syncthreads();
    for (int off = 1; off < 512; off <<= 1) {
        int x = (tid >= off) ? ts[tid - off] : 0;
        __syncthreads();
        ts[tid] += x;
        __syncthreads();
    }
    int ex = ts[tid] - v;
    if (tid <= nbuck) bbase[tid] = ex;
    if (tid < nbuck)  bcur[tid]  = ex;
}

__global__ __launch_bounds__(256) void k_bscatter(
    const int* __restrict__ src, const int* __restrict__ dst,
    int* __restrict__ bcur, int2* __restrict__ ebuf, int e)
{
    __shared__ int hist[512];
    __shared__ int lbase[512];
    __shared__ int lrun[512];
    const int tid = threadIdx.x;
    hist[tid] = 0; hist[tid + 256] = 0;
    __syncthreads();
    const int i0 = blockIdx.x * CHUNK;
    #pragma unroll
    for (int t = 0; t < CHUNK / 256; ++t) {
        int i = i0 + t * 256 + tid;
        if (i < e) atomicAdd(&hist[dst[i] >> BSH], 1);
    }
    __syncthreads();
    for (int j = tid; j < 512; j += 256) {
        int c = hist[j];
        lrun[j] = 0;
        if (c) lbase[j] = atomicAdd(&bcur[j], c);
    }
    __syncthreads();
    #pragma unroll
    for (int t = 0; t < CHUNK / 256; ++t) {
        int i = i0 + t * 256 + tid;
        if (i < e) {
            int d = dst[i];
            int b = d >> BSH;
            int r = atomicAdd(&lrun[b], 1);
            ebuf[lbase[b] + r] = make_int2(src[i], d);
        }
    }
}

__global__ __launch_bounds__(256) void k_bbuild(
    const int2* __restrict__ ebuf, const int* __restrict__ bbase,
    int* __restrict__ cnt, int* __restrict__ offs, int* __restrict__ csrc, int n)
{
    __shared__ int ncnt[256];
    __shared__ int ts[256];
    __shared__ int nrun[256];
    const int tid = threadIdx.x;
    const int b = blockIdx.x;
    const int node0 = b << BSH;
    const int nn = min(256, n - node0);
    const int s = bbase[b];
    const int epb = bbase[b + 1] - s;

    ncnt[tid] = 0;
    __syncthreads();
    for (int i = tid; i < epb; i += 256)
        atomicAdd(&ncnt[ebuf[s + i].y & 255], 1);
    __syncthreads();
    int v = ncnt[tid];
    ts[tid] = v;
    __syncthreads();
    for (int off = 1; off < 256; off <<= 1) {
        int x = (tid >= off) ? ts[tid - off] : 0;
        __syncthreads();
        ts[tid] += x;
        __syncthreads();
    }
    int ex = ts[tid] - v;
    if (tid < nn) { cnt[node0 + tid] = v; offs[node0 + tid] = s + ex; }
    nrun[tid] = 0;
    __syncthreads();
    ncnt[tid] = ex;
    __syncthreads();
    for (int i = tid; i < epb; i += 256) {
        int2 p = ebuf[s + i];
        int d = p.y & 255;
        int r = atomicAdd(&nrun[d], 1);
        csrc[s + ncnt[d] + r] = p.x;
    }
}

// ---------------------------------------------------------------------------
// Edge attention (unchanged): single pass, no max subtraction.
// ---------------------------------------------------------------------------
__global__ __launch_bounds__(256) void k_edge(
    const u16* __restrict__ Qb, const u16* __restrict__ Kb, const u16* __restrict__ Vb,
    const int* __restrict__ offs, const int* __restrict__ cnt, const int* __restrict__ csrc,
    u16* __restrict__ hnew, int n)
{
    const int wid  = threadIdx.x >> 6;
    const int lane = threadIdx.x & 63;
    const int node = blockIdx.x * 4 + wid;
    if (node >= n) return;
    const int start = offs[node];
    const int deg   = cnt[node];

    const u32 qu = *(const u32*)&Qb[(size_t)node * 128 + lane * 2];
    const float q0 = b2f((u16)(qu & 0xFFFF));
    const float q1 = b2f((u16)(qu >> 16));

    float denom = 0.f, o0 = 0.f, o1 = 0.f;

    for (int base = 0; base < deg; base += 64) {
        int m = deg - base; if (m > 64) m = 64;
        int myidx = 0;
        if (lane < m) myidx = csrc[start + base + lane];
        int j = 0;
        for (; j + 4 <= m; j += 4) {
            int s0 = __shfl(myidx, j + 0);
            int s1 = __shfl(myidx, j + 1);
            int s2 = __shfl(myidx, j + 2);
            int s3 = __shfl(myidx, j + 3);
            const u32 k0 = *(const u32*)&Kb[(size_t)s0 * 128 + lane * 2];
            const u32 k1 = *(const u32*)&Kb[(size_t)s1 * 128 + lane * 2];
            const u32 k2 = *(const u32*)&Kb[(size_t)s2 * 128 + lane * 2];
            const u32 k3 = *(const u32*)&Kb[(size_t)s3 * 128 + lane * 2];
            const u32 v0 = *(const u32*)&Vb[(size_t)s0 * 128 + lane * 2];
            const u32 v1 = *(const u32*)&Vb[(size_t)s1 * 128 + lane * 2];
            const u32 v2 = *(const u32*)&Vb[(size_t)s2 * 128 + lane * 2];
            const u32 v3 = *(const u32*)&Vb[(size_t)s3 * 128 + lane * 2];
            float p0 = q0 * b2f((u16)(k0 & 0xFFFF)) + q1 * b2f((u16)(k0 >> 16));
            float p1 = q0 * b2f((u16)(k1 & 0xFFFF)) + q1 * b2f((u16)(k1 >> 16));
            float p2 = q0 * b2f((u16)(k2 & 0xFFFF)) + q1 * b2f((u16)(k2 >> 16));
            float p3 = q0 * b2f((u16)(k3 & 0xFFFF)) + q1 * b2f((u16)(k3 >> 16));
            p0 += __shfl_xor(p0, 1); p1 += __shfl_xor(p1, 1); p2 += __shfl_xor(p2, 1); p3 += __shfl_xor(p3, 1);
            p0 += __shfl_xor(p0, 2); p1 += __shfl_xor(p1, 2); p2 += __shfl_xor(p2, 2); p3 += __shfl_xor(p3, 2);
            p0 += __shfl_xor(p0, 4); p1 += __shfl_xor(p1, 4); p2 += __shfl_xor(p2, 4); p3 += __shfl_xor(p3, 4);
            p0 += __shfl_xor(p0, 8); p1 += __shfl_xor(p1, 8); p2 += __shfl_xor(p2, 8); p3 += __shfl_xor(p3, 8);
            float w0 = __expf(p0 * ATT_SCALE);
            float w1 = __expf(p1 * ATT_SCALE);
            float w2 = __expf(p2 * ATT_SCALE);
            float w3 = __expf(p3 * ATT_SCALE);
            denom += (w0 + w1) + (w2 + w3);
            o0 = fmaf(w0, b2f((u16)(v0 & 0xFFFF)), o0); o1 = fmaf(w0, b2f((u16)(v0 >> 16)), o1);
            o0 = fmaf(w1, b2f((u16)(v1 & 0xFFFF)), o0); o1 = fmaf(w1, b2f((u16)(v1 >> 16)), o1);
            o0 = fmaf(w2, b2f((u16)(v2 & 0xFFFF)), o0); o1 = fmaf(w2, b2f((u16)(v2 >> 16)), o1);
            o0 = fmaf(w3, b2f((u16)(v3 & 0xFFFF)), o0); o1 = fmaf(w3, b2f((u16)(v3 >> 16)), o1);
        }
        for (; j < m; ++j) {
            int s = __shfl(myidx, j);
            const u32 kk = *(const u32*)&Kb[(size_t)s * 128 + lane * 2];
            const u32 vv = *(const u32*)&Vb[(size_t)s * 128 + lane * 2];
            float p = q0 * b2f((u16)(kk & 0xFFFF)) + q1 * b2f((u16)(kk >> 16));
            p += __shfl_xor(p, 1); p += __shfl_xor(p, 2); p += __shfl_xor(p, 4); p += __shfl_xor(p, 8);
            float w = __expf(p * ATT_SCALE);
            denom += w;
            o0 = fmaf(w, b2f((u16)(vv & 0xFFFF)), o0);
            o1 = fmaf(w, b2f((u16)(vv >> 16)), o1);
        }
    }
    float inv = (deg > 0) ? (1.f / denom) : 0.f;
    u16 r0_ = f2b(o0 * inv), r1_ = f2b(o1 * inv);
    *(u32*)&hnew[(size_t)node * 128 + lane * 2] = (u32)r0_ | ((u32)r1_ << 16);
}

// ---------------------------------------------------------------------------
// Tail: h1 = h + hnew@Wo + bo (regs); h2 = LN2(h1) -> LDS transpose ->
// FFN1+ReLU -> LDS transpose -> FFN2 + h1 -> LDS transpose -> out (float4).
// One kernel, zero intermediate HBM traffic.
// ---------------------------------------------------------------------------
__global__ __launch_bounds__(256) void k_tail(
    const u16* __restrict__ hnew, const u16* __restrict__ Bo, const float* __restrict__ bo,
    const float* __restrict__ h, const float* __restrict__ g2, const float* __restrict__ be2,
    const u16* __restrict__ B1, const float* __restrict__ b1,
    const u16* __restrict__ B2, const float* __restrict__ b2,
    float* __restrict__ out, int M)
{
    __shared__ u16 smem[4][4096];                 // 8 KB per wave
    const int wid = threadIdx.x >> 6;
    const int l   = threadIdx.x & 63;
    int slab = blockIdx.x * 4 + wid;
    const bool valid = (slab * 16) < M;
    if (!valid) slab = 0;
    const int r0  = slab * 16;
    const int col = l & 15, hg = l >> 4;
    u16* ws = smem[wid];

    // ---- Wo GEMM + residual; h1 in regs; LN2 stats ----
    const u16* ar = hnew + (size_t)(r0 + col) * 128 + hg * 8;
    bf16x8 a0 = *(const bf16x8*)(ar);
    bf16x8 a1 = *(const bf16x8*)(ar + 32);
    bf16x8 a2 = *(const bf16x8*)(ar + 64);
    bf16x8 a3 = *(const bf16x8*)(ar + 96);
    float h1v[8][4];
    float s[4] = {0, 0, 0, 0}, s2[4] = {0, 0, 0, 0};
    #pragma unroll
    for (int t = 0; t < 8; ++t) {
        float bb = bo[t * 16 + col];
        f32x4 c = {bb, bb, bb, bb};
        const u16* bp = Bo + t * 2048 + l * 8;
        c = MFMA(a0, *(const bf16x8*)(bp),        c);
        c = MFMA(a1, *(const bf16x8*)(bp + 512),  c);
        c = MFMA(a2, *(const bf16x8*)(bp + 1024), c);
        c = MFMA(a3, *(const bf16x8*)(bp + 1536), c);
        #pragma unroll
        for (int r = 0; r < 4; ++r) {
            float x = c[r] + h[(size_t)(r0 + hg * 4 + r) * 128 + t * 16 + col];
            h1v[t][r] = x;
            s[r] += x; s2[r] += x * x;
        }
    }
    float mean[4], rs[4];
    #pragma unroll
    for (int r = 0; r < 4; ++r) {
        float a = s[r], b = s2[r];
        a += __shfl_xor(a, 1); b += __shfl_xor(b, 1);
        a += __shfl_xor(a, 2); b += __shfl_xor(b, 2);
        a += __shfl_xor(a, 4); b += __shfl_xor(b, 4);
        a += __shfl_xor(a, 8); b += __shfl_xor(b, 8);
        mean[r] = a * (1.f / 128.f);
        float var = b * (1.f / 128.f) - mean[r] * mean[r];
        rs[r] = rsqrtf(var + EPS);
    }
    // h2 = LN2(h1) -> LDS [16][128] bf16, swizzled
    #pragma unroll
    for (int t = 0; t < 8; ++t) {
        float g  = g2[t * 16 + col];
        float be = be2[t * 16 + col];
        #pragma unroll
        for (int r = 0; r < 4; ++r)
            ws[swz(hg * 4 + r, t * 16 + col, 128)] =
                f2b((h1v[t][r] - mean[r]) * rs[r] * g + be);
    }
    __syncthreads();
    // ---- FFN1 A-frags from LDS ----
    bf16x8 f1[4];
    #pragma unroll
    for (int i = 0; i < 4; ++i)
        f1[i] = *(const bf16x8*)&ws[swz(col, i * 32 + hg * 8, 128)];
    __syncthreads();                              // WAR before [16][256] writes
    // ---- FFN1 + ReLU -> LDS [16][256] bf16 ----
    #pragma unroll
    for (int t = 0; t < 16; ++t) {
        float bb = b1[t * 16 + col];
        f32x4 c = {bb, bb, bb, bb};
        const u16* bp = B1 + t * 2048 + l * 8;
        c = MFMA(f1[0], *(const bf16x8*)(bp),        c);
        c = MFMA(f1[1], *(const bf16x8*)(bp + 512),  c);
        c = MFMA(f1[2], *(const bf16x8*)(bp + 1024), c);
        c = MFMA(f1[3], *(const bf16x8*)(bp + 1536), c);
        #pragma unroll
        for (int r = 0; r < 4; ++r)
            ws[swz(hg * 4 + r, t * 16 + col, 256)] = f2b(fmaxf(c[r], 0.f));
    }
    __syncthreads();
    // ---- FFN2 A-frags from LDS ----
    bf16x8 f2[8];
    #pragma unroll
    for (int i = 0; i < 8; ++i)
        f2[i] = *(const bf16x8*)&ws[swz(col, i * 32 + hg * 8, 256)];
    __syncthreads();                              // WAR before f32 reuse of ws
    // ---- FFN2 + h1 -> LDS f32 [16][128] ----
    float* wsf = (float*)ws;
    #pragma unroll
    for (int t = 0; t < 8; ++t) {
        float bb = b2[t * 16 + col];
        f32x4 c = {bb, bb, bb, bb};
        const u16* bp = B2 + t * 4096 + l * 8;
        #pragma unroll
        for (int kc = 0; kc < 8; ++kc)
            c = MFMA(f2[kc], *(const bf16x8*)(bp + kc * 512), c);
        #pragma unroll
        for (int r = 0; r < 4; ++r)
            wsf[swzf(hg * 4 + r, t * 16 + col)] = c[r] + h1v[t][r];
    }
    __syncthreads();
    // ---- vectorized out store ----
    if (valid) {
        #pragma unroll
        for (int i = 0; i < 8; ++i) {
            int row = i * 2 + (l >> 5);
            int cg  = l & 31;
            float4 v = *(const float4*)&wsf[swzf(row, cg * 4)];
            *(float4*)&out[(size_t)(r0 + row) * 128 + cg * 4] = v;
        }
    }
}

// ---------------------------------------------------------------------------
extern "C" void kernel_launch(void* const* d_in, const int* in_sizes, int n_in,
                              void* d_out, int out_size, void* d_ws, size_t ws_size,
                              hipStream_t stream)
{
    const float* h   = (const float*)d_in[0];
    const int*   src = (const int*)  d_in[1];
    const int*   dst = (const int*)  d_in[2];
    const float* Wq  = (const float*)d_in[3];
    const float* bq  = (const float*)d_in[4];
    const float* Wk  = (const float*)d_in[5];
    const float* bk  = (const float*)d_in[6];
    const float* Wv  = (const float*)d_in[7];
    const float* bv  = (const float*)d_in[8];
    const float* Wo  = (const float*)d_in[9];
    const float* bo  = (const float*)d_in[10];
    const float* W1  = (const float*)d_in[11];
    const float* b1  = (const float*)d_in[12];
    const float* W2  = (const float*)d_in[13];
    const float* b2  = (const float*)d_in[14];
    const float* g1  = (const float*)d_in[15];
    const float* be1 = (const float*)d_in[16];
    const float* g2  = (const float*)d_in[17];
    const float* be2 = (const float*)d_in[18];

    const int n = in_sizes[0] / HIDN;    // 100000
    const int e = in_sizes[1];           // 1600000
    float* out = (float*)d_out;

    const int nbuck = (n + 255) >> BSH;

    // --- workspace layout ---
    char* p = (char*)d_ws;
    int* csrc  = (int*)p;              p += (size_t)e * 4;
    int* cnt   = (int*)p;              p += (size_t)n * 4;
    int* offs  = (int*)p;              p += (size_t)n * 4;
    int* bcnt  = (int*)p;              p += 512 * 4;
    int* bbase = (int*)p;              p += 512 * 4;
    int* bcur  = (int*)p;              p += 512 * 4;
    u16* wpack = (u16*)p;              p += 131072 * 2;      // 256 KB packed weights
    const size_t NB = (size_t)n * HIDN * 2;                  // bf16 activation buffer
    u16* Qb   = (u16*)p;               p += NB;
    u16* Kb   = (u16*)p;               p += NB;
    u16* Vb   = (u16*)p;               p += NB;
    u16* hnew = (u16*)p;               p += NB;
    int2* ebuf = (int2*)p;             p += (size_t)e * 8;

    u16* Wq_p = wpack;
    u16* Wk_p = wpack + 16384;
    u16* Wv_p = wpack + 32768;
    u16* Wo_p = wpack + 49152;
    u16* W1_p = wpack + 65536;
    u16* W2_p = wpack + 98304;

    const int nslab = (n + 15) / 16;
    const int gemm_blocks = (nslab + 3) / 4;
    const int echunks = (e + CHUNK - 1) / CHUNK;

    hipMemsetAsync(bcnt, 0, 512 * sizeof(int), stream);

    k_bcount  <<<echunks, 256, 0, stream>>>(dst, bcnt, e);
    k_bscan   <<<1, 512, 0, stream>>>(bcnt, bbase, bcur, nbuck);
    k_bscatter<<<echunks, 256, 0, stream>>>(src, dst, bcur, ebuf, e);
    k_bbuild  <<<nbuck, 256, 0, stream>>>(ebuf, bbase, cnt, offs, csrc, n);

    k_pack_all<<<64, 256, 0, stream>>>(Wq, Wk, Wv, Wo, W1, W2, wpack);

    k_qkv <<<gemm_blocks, 256, 0, stream>>>(h, g1, be1, Wq_p, Wk_p, Wv_p,
                                            bq, bk, bv, Qb, Kb, Vb, n);

    k_edge<<<(n + 3) / 4, 256, 0, stream>>>(Qb, Kb, Vb, offs, cnt, csrc, hnew, n);

    k_tail<<<gemm_blocks, 256, 0, stream>>>(hnew, Wo_p, bo, h, g2, be2,
                                            W1_p, b1, W2_p, b2, out, n);
}

// Round 8
// 464.606 us; speedup vs baseline: 1.0448x; 1.0448x over previous
//
#include <hip/hip_runtime.h>
#include <math.h>

#define HIDN 128
#define EPS 1e-5f
#define ATT_SCALE 0.17677669529663687f   // 32^-0.5

typedef unsigned int  u32;
typedef unsigned short u16;
typedef __attribute__((ext_vector_type(8))) short bf16x8;   // 8 bf16 in 4 VGPRs
typedef __attribute__((ext_vector_type(4))) float f32x4;
typedef __attribute__((ext_vector_type(2))) _Float16 h16x2; // packed fp16 pair

__device__ __forceinline__ u16 f2b(float x) {           // fp32 -> bf16 RNE
    u32 u = __float_as_uint(x);
    u += 0x7FFFu + ((u >> 16) & 1u);
    return (u16)(u >> 16);
}
__device__ __forceinline__ float b2f(u16 x) { return __uint_as_float(((u32)x) << 16); }
__device__ __forceinline__ u16 f2h(float x) {           // fp32 -> fp16 RNE
    _Float16 h = (_Float16)x;
    u16 r; __builtin_memcpy(&r, &h, 2); return r;
}
__device__ __forceinline__ h16x2 u2h(u32 a) { h16x2 r; __builtin_memcpy(&r, &a, 4); return r; }

// packed fp16 dot: c += a.x*b.x + a.y*b.y
__device__ __forceinline__ float dot2f(u32 a, u32 b, float c) {
    h16x2 ah = u2h(a), bh = u2h(b);
#if __has_builtin(__builtin_amdgcn_fdot2)
    return __builtin_amdgcn_fdot2(ah, bh, c, false);
#else
    return c + (float)ah.x * (float)bh.x + (float)ah.y * (float)bh.y;
#endif
}

#define MFMA(a, b, c) __builtin_amdgcn_mfma_f32_16x16x32_bf16((a), (b), (c), 0, 0, 0)

// XOR-swizzled LDS index (u16 elements, 16B granules).
__device__ __forceinline__ int swz(int row, int kpos, int rowstride) {
    return row * rowstride + ((((kpos >> 3) ^ (row & 7)) << 3) | (kpos & 7));
}

// ---------------------------------------------------------------------------
// Pack all 6 weight matrices into MFMA B-fragment order, bf16.
// ---------------------------------------------------------------------------
__global__ __launch_bounds__(256) void k_pack_all(
    const float* __restrict__ Wq, const float* __restrict__ Wk, const float* __restrict__ Wv,
    const float* __restrict__ Wo, const float* __restrict__ W1, const float* __restrict__ W2,
    u16* __restrict__ out)
{
    int idx = blockIdx.x * 256 + threadIdx.x;
    const float* W; int K, N, base, local;
    if      (idx <  2048) { W = Wq; K = 128; N = 128; base = 0;     local = idx; }
    else if (idx <  4096) { W = Wk; K = 128; N = 128; base = 16384; local = idx - 2048; }
    else if (idx <  6144) { W = Wv; K = 128; N = 128; base = 32768; local = idx - 4096; }
    else if (idx <  8192) { W = Wo; K = 128; N = 128; base = 49152; local = idx - 6144; }
    else if (idx < 12288) { W = W1; K = 128; N = 256; base = 65536; local = idx - 8192; }
    else if (idx < 16384) { W = W2; K = 256; N = 128; base = 98304; local = idx - 12288; }
    else return;
    const int KC = K >> 5;
    const int l  = local & 63;
    const int tc = local >> 6;
    const int c  = tc % KC;
    const int t  = tc / KC;
    const int col = l & 15, hg = l >> 4;
    const int kbase = c * 32 + hg * 8;
    u16 v[8];
    #pragma unroll
    for (int j = 0; j < 8; ++j) v[j] = f2b(W[(size_t)(kbase + j) * N + t * 16 + col]);
    uint4 o;
    o.x = (u32)v[0] | ((u32)v[1] << 16);
    o.y = (u32)v[2] | ((u32)v[3] << 16);
    o.z = (u32)v[4] | ((u32)v[5] << 16);
    o.w = (u32)v[6] | ((u32)v[7] << 16);
    *(uint4*)&out[base + local * 8] = o;
}

// ---------------------------------------------------------------------------
// QKV fused with LN1.  Outputs for the edge kernel:
//   Qh : [node][128] fp16 (linear)
//   KVb: [node][256 u16] interleaved: u32 seq {K01,V01,K23,V23,...} per 8 dims
//        (K dim d at u16 idx (d>>1)*4+(d&1); V dim d at +2)
// ---------------------------------------------------------------------------
__global__ __launch_bounds__(256) void k_qkv(
    const float* __restrict__ h, const float* __restrict__ g1, const float* __restrict__ be1,
    const u16* __restrict__ Bq, const u16* __restrict__ Bk, const u16* __restrict__ Bv,
    const float* __restrict__ bq, const float* __restrict__ bk, const float* __restrict__ bv,
    u16* __restrict__ Qh, u16* __restrict__ KVb, int M)
{
    __shared__ u16 smem[4][4096];                 // 8 KB per wave: [16][256] u16
    const int wid = threadIdx.x >> 6;
    const int l   = threadIdx.x & 63;
    int slab = blockIdx.x * 4 + wid;
    const bool valid = (slab * 16) < M;
    if (!valid) slab = 0;
    const int r0  = slab * 16;
    const int col = l & 15, hg = l >> 4;
    u16* ws = smem[wid];

    // ---- load 32 fp32 of my row, LN stats (4 lanes/row: xor 16,32) ----
    float av[4][8];
    const float* hr = h + (size_t)(r0 + col) * 128 + hg * 8;
    #pragma unroll
    for (int c = 0; c < 4; ++c) {
        float4 p0 = *(const float4*)&hr[c * 32];
        float4 p1 = *(const float4*)&hr[c * 32 + 4];
        av[c][0] = p0.x; av[c][1] = p0.y; av[c][2] = p0.z; av[c][3] = p0.w;
        av[c][4] = p1.x; av[c][5] = p1.y; av[c][6] = p1.z; av[c][7] = p1.w;
    }
    float s = 0.f, q2 = 0.f;
    #pragma unroll
    for (int c = 0; c < 4; ++c)
        #pragma unroll
        for (int j = 0; j < 8; ++j) { float v = av[c][j]; s += v; q2 += v * v; }
    s  += __shfl_xor(s, 16);  s  += __shfl_xor(s, 32);
    q2 += __shfl_xor(q2, 16); q2 += __shfl_xor(q2, 32);
    float mean = s * (1.f / 128.f);
    float var  = q2 * (1.f / 128.f) - mean * mean;
    float rs   = rsqrtf(var + EPS);

    // ---- normalize -> bf16 A-frags ----
    bf16x8 af[4];
    #pragma unroll
    for (int c = 0; c < 4; ++c) {
        u32 w[4];
        #pragma unroll
        for (int jj = 0; jj < 4; ++jj) {
            int k0 = c * 32 + hg * 8 + 2 * jj;
            float v0 = (av[c][2 * jj]     - mean) * rs * g1[k0]     + be1[k0];
            float v1 = (av[c][2 * jj + 1] - mean) * rs * g1[k0 + 1] + be1[k0 + 1];
            w[jj] = (u32)f2b(v0) | ((u32)f2b(v1) << 16);
        }
        uint4 uu = make_uint4(w[0], w[1], w[2], w[3]);
        af[c] = *(bf16x8*)&uu;
    }

    // ---- Q GEMM -> ws (fp16) -> vector store ----
    #pragma unroll
    for (int t = 0; t < 8; ++t) {
        float bb = bq[t * 16 + col];
        f32x4 c = {bb, bb, bb, bb};
        const u16* bp = Bq + t * 2048 + l * 8;
        c = MFMA(af[0], *(const bf16x8*)(bp),        c);
        c = MFMA(af[1], *(const bf16x8*)(bp + 512),  c);
        c = MFMA(af[2], *(const bf16x8*)(bp + 1024), c);
        c = MFMA(af[3], *(const bf16x8*)(bp + 1536), c);
        #pragma unroll
        for (int r = 0; r < 4; ++r)
            ws[swz(hg * 4 + r, t * 16 + col, 256)] = f2h(c[r]);
    }
    __syncthreads();
    if (valid) {
        #pragma unroll
        for (int i = 0; i < 4; ++i) {
            int row = i * 4 + (l >> 4);
            int cg  = l & 15;
            bf16x8 vv = *(const bf16x8*)&ws[swz(row, cg * 8, 256)];
            *(bf16x8*)&Qh[(size_t)(r0 + row) * 128 + cg * 8] = vv;
        }
    }
    __syncthreads();

    // ---- K GEMM -> ws interleaved slots ----
    #pragma unroll
    for (int t = 0; t < 8; ++t) {
        float bb = bk[t * 16 + col];
        f32x4 c = {bb, bb, bb, bb};
        const u16* bp = Bk + t * 2048 + l * 8;
        c = MFMA(af[0], *(const bf16x8*)(bp),        c);
        c = MFMA(af[1], *(const bf16x8*)(bp + 512),  c);
        c = MFMA(af[2], *(const bf16x8*)(bp + 1024), c);
        c = MFMA(af[3], *(const bf16x8*)(bp + 1536), c);
        int cc = t * 16 + col;
        int kp = ((cc >> 1) << 2) | (cc & 1);
        #pragma unroll
        for (int r = 0; r < 4; ++r)
            ws[swz(hg * 4 + r, kp, 256)] = f2h(c[r]);
    }
    // ---- V GEMM -> ws interleaved slots (disjoint cells from K) ----
    #pragma unroll
    for (int t = 0; t < 8; ++t) {
        float bb = bv[t * 16 + col];
        f32x4 c = {bb, bb, bb, bb};
        const u16* bp = Bv + t * 2048 + l * 8;
        c = MFMA(af[0], *(const bf16x8*)(bp),        c);
        c = MFMA(af[1], *(const bf16x8*)(bp + 512),  c);
        c = MFMA(af[2], *(const bf16x8*)(bp + 1024), c);
        c = MFMA(af[3], *(const bf16x8*)(bp + 1536), c);
        int cc = t * 16 + col;
        int kp = ((cc >> 1) << 2) | 2 | (cc & 1);
        #pragma unroll
        for (int r = 0; r < 4; ++r)
            ws[swz(hg * 4 + r, kp, 256)] = f2h(c[r]);
    }
    __syncthreads();
    if (valid) {
        #pragma unroll
        for (int i = 0; i < 8; ++i) {
            int row = i * 2 + (l >> 5);
            int g   = l & 31;
            bf16x8 vv = *(const bf16x8*)&ws[swz(row, g * 8, 256)];
            *(bf16x8*)&KVb[(size_t)(r0 + row) * 256 + g * 8] = vv;
        }
    }
}

// ---------------------------------------------------------------------------
// CSR build, two-level (bucket = 256 consecutive dst nodes).
// ---------------------------------------------------------------------------
#define BSH 8
#define CHUNK 4096

__global__ __launch_bounds__(256) void k_bcount(
    const int* __restrict__ dst, int* __restrict__ bcnt, int e)
{
    __shared__ int hist[512];
    const int tid = threadIdx.x;
    hist[tid] = 0; hist[tid + 256] = 0;
    __syncthreads();
    const int i0 = blockIdx.x * CHUNK;
    #pragma unroll
    for (int t = 0; t < CHUNK / 256; ++t) {
        int i = i0 + t * 256 + tid;
        if (i < e) atomicAdd(&hist[dst[i] >> BSH], 1);
    }
    __syncthreads();
    for (int j = tid; j < 512; j += 256) {
        int c = hist[j];
        if (c) atomicAdd(&bcnt[j], c);
    }
}

__global__ __launch_bounds__(512) void k_bscan(
    const int* __restrict__ bcnt, int* __restrict__ bbase, int* __restrict__ bcur, int nbuck)
{
    __shared__ int ts[512];
    const int tid = threadIdx.x;
    int v = (tid < nbuck) ? bcnt[tid] : 0;
    ts[tid] = v;
    __syncthreads();
    for (int off = 1; off < 512; off <<= 1) {
        int x = (tid >= off) ? ts[tid - off] : 0;
        __syncthreads();
        ts[tid] += x;
        __syncthreads();
    }
    int ex = ts[tid] - v;
    if (tid <= nbuck) bbase[tid] = ex;
    if (tid < nbuck)  bcur[tid]  = ex;
}

__global__ __launch_bounds__(256) void k_bscatter(
    const int* __restrict__ src, const int* __restrict__ dst,
    int* __restrict__ bcur, int2* __restrict__ ebuf, int e)
{
    __shared__ int hist[512];
    __shared__ int lbase[512];
    __shared__ int lrun[512];
    const int tid = threadIdx.x;
    hist[tid] = 0; hist[tid + 256] = 0;
    __syncthreads();
    const int i0 = blockIdx.x * CHUNK;
    #pragma unroll
    for (int t = 0; t < CHUNK / 256; ++t) {
        int i = i0 + t * 256 + tid;
        if (i < e) atomicAdd(&hist[dst[i] >> BSH], 1);
    }
    __syncthreads();
    for (int j = tid; j < 512; j += 256) {
        int c = hist[j];
        lrun[j] = 0;
        if (c) lbase[j] = atomicAdd(&bcur[j], c);
    }
    __syncthreads();
    #pragma unroll
    for (int t = 0; t < CHUNK / 256; ++t) {
        int i = i0 + t * 256 + tid;
        if (i < e) {
            int d = dst[i];
            int b = d >> BSH;
            int r = atomicAdd(&lrun[b], 1);
            ebuf[lbase[b] + r] = make_int2(src[i], d);
        }
    }
}

__global__ __launch_bounds__(256) void k_bbuild(
    const int2* __restrict__ ebuf, const int* __restrict__ bbase,
    int* __restrict__ cnt, int* __restrict__ offs, int* __restrict__ csrc, int n)
{
    __shared__ int ncnt[256];
    __shared__ int ts[256];
    __shared__ int nrun[256];
    const int tid = threadIdx.x;
    const int b = blockIdx.x;
    const int node0 = b << BSH;
    const int nn = min(256, n - node0);
    const int s = bbase[b];
    const int epb = bbase[b + 1] - s;

    ncnt[tid] = 0;
    __syncthreads();
    for (int i = tid; i < epb; i += 256)
        atomicAdd(&ncnt[ebuf[s + i].y & 255], 1);
    __syncthreads();
    int v = ncnt[tid];
    ts[tid] = v;
    __syncthreads();
    for (int off = 1; off < 256; off <<= 1) {
        int x = (tid >= off) ? ts[tid - off] : 0;
        __syncthreads();
        ts[tid] += x;
        __syncthreads();
    }
    int ex = ts[tid] - v;
    if (tid < nn) { cnt[node0 + tid] = v; offs[node0 + tid] = s + ex; }
    nrun[tid] = 0;
    __syncthreads();
    ncnt[tid] = ex;
    __syncthreads();
    for (int i = tid; i < epb; i += 256) {
        int2 p = ebuf[s + i];
        int d = p.y & 255;
        int r = atomicAdd(&nrun[d], 1);
        csrc[s + ncnt[d] + r] = p.x;
    }
}

// ---------------------------------------------------------------------------
// Edge attention, 4 edge-slots per wave (16 lanes/edge, 8 dims/lane, fp16).
// Per 4 edges: 1 bperm idx + 2 dwordx4 KV gathers/lane + 4 dot2 + 2 shfl +
// exp + 4 pk_fma.  Cross-slot reduce once per node.  Single pass (no max
// subtraction: scores O(1), softmax shift-invariant).
// ---------------------------------------------------------------------------
__global__ __launch_bounds__(256) void k_edge(
    const u16* __restrict__ Qh, const u16* __restrict__ KVb,
    const int* __restrict__ offs, const int* __restrict__ cnt, const int* __restrict__ csrc,
    u16* __restrict__ hnew, int n)
{
    const int wid  = threadIdx.x >> 6;
    const int l    = threadIdx.x & 63;
    const int node = blockIdx.x * 4 + wid;
    if (node >= n) return;
    const int start = offs[node];
    const int deg   = cnt[node];
    const int w    = l & 15;       // dims 8w..8w+7 (head = w>>2)
    const int slot = l >> 4;       // edge slot 0..3

    const uint4 q = *(const uint4*)&Qh[(size_t)node * 128 + w * 8];

    h16x2 o0 = {0, 0}, o1 = {0, 0}, o2 = {0, 0}, o3 = {0, 0};
    float denom = 0.f;

    for (int base = 0; base < deg; base += 64) {
        int m = deg - base; if (m > 64) m = 64;
        int myidx = 0;
        if (l < m) myidx = csrc[start + base + l];
        for (int j = 0; j < m; j += 4) {
            int eloc = j + slot;
            int s = __shfl(myidx, eloc & 63);
            const u16* kvr = KVb + (size_t)s * 256 + w * 16;
            uint4 kv0 = *(const uint4*)(kvr);
            uint4 kv1 = *(const uint4*)(kvr + 8);
            float p = dot2f(kv0.x, q.x, 0.f);
            p = dot2f(kv0.z, q.y, p);
            p = dot2f(kv1.x, q.z, p);
            p = dot2f(kv1.z, q.w, p);
            p += __shfl_xor(p, 1);
            p += __shfl_xor(p, 2);
            float al = __expf(p * ATT_SCALE);
            al = (eloc < m) ? al : 0.f;
            denom += al;
            h16x2 a2; a2.x = (_Float16)al; a2.y = a2.x;
            o0 += a2 * u2h(kv0.y);
            o1 += a2 * u2h(kv0.w);
            o2 += a2 * u2h(kv1.y);
            o3 += a2 * u2h(kv1.w);
        }
    }

    // cross-slot reduce (lanes l, l^16, l^32 hold same dims)
    float of[8];
    of[0] = (float)o0.x; of[1] = (float)o0.y; of[2] = (float)o1.x; of[3] = (float)o1.y;
    of[4] = (float)o2.x; of[5] = (float)o2.y; of[6] = (float)o3.x; of[7] = (float)o3.y;
    #pragma unroll
    for (int msk = 16; msk <= 32; msk <<= 1) {
        #pragma unroll
        for (int i = 0; i < 8; ++i) of[i] += __shfl_xor(of[i], msk);
        denom += __shfl_xor(denom, msk);
    }
    float inv = (deg > 0) ? (1.f / denom) : 0.f;
    if (slot == 0) {
        u32 wrd[4];
        #pragma unroll
        for (int i = 0; i < 4; ++i)
            wrd[i] = (u32)f2b(of[2 * i] * inv) | ((u32)f2b(of[2 * i + 1] * inv) << 16);
        uint4 uu = make_uint4(wrd[0], wrd[1], wrd[2], wrd[3]);
        *(uint4*)&hnew[(size_t)node * 128 + w * 8] = uu;
    }
}

// ---------------------------------------------------------------------------
// Attn-out + residual + LN2 (round-6 form): h1 fp32, h2 bf16.
// ---------------------------------------------------------------------------
__global__ __launch_bounds__(256) void k_attnout(
    const u16* __restrict__ hnew, const u16* __restrict__ Bo, const float* __restrict__ bo,
    const float* __restrict__ h, const float* __restrict__ g2, const float* __restrict__ be2,
    float* __restrict__ h1, u16* __restrict__ h2, int M)
{
    const int slab = blockIdx.x * 4 + (threadIdx.x >> 6);
    const int l = threadIdx.x & 63;
    const int r0 = slab * 16;
    if (r0 >= M) return;
    const int col = l & 15, hg = l >> 4;
    const u16* ar = hnew + (size_t)(r0 + col) * 128 + hg * 8;
    bf16x8 a0 = *(const bf16x8*)(ar);
    bf16x8 a1 = *(const bf16x8*)(ar + 32);
    bf16x8 a2 = *(const bf16x8*)(ar + 64);
    bf16x8 a3 = *(const bf16x8*)(ar + 96);
    f32x4 acc[8];
    #pragma unroll
    for (int t = 0; t < 8; ++t) {
        float bb = bo[t * 16 + col];
        f32x4 c = {bb, bb, bb, bb};
        const u16* bp = Bo + t * 2048 + l * 8;
        c = MFMA(a0, *(const bf16x8*)(bp),        c);
        c = MFMA(a1, *(const bf16x8*)(bp + 512),  c);
        c = MFMA(a2, *(const bf16x8*)(bp + 1024), c);
        c = MFMA(a3, *(const bf16x8*)(bp + 1536), c);
        acc[t] = c;
    }
    float s[4] = {0, 0, 0, 0}, s2[4] = {0, 0, 0, 0};
    #pragma unroll
    for (int t = 0; t < 8; ++t) {
        #pragma unroll
        for (int r = 0; r < 4; ++r) {
            float x = acc[t][r] + h[(size_t)(r0 + hg * 4 + r) * 128 + t * 16 + col];
            acc[t][r] = x;
            s[r] += x; s2[r] += x * x;
        }
    }
    float mean[4], rs[4];
    #pragma unroll
    for (int r = 0; r < 4; ++r) {
        float a = s[r], b = s2[r];
        a += __shfl_xor(a, 1); b += __shfl_xor(b, 1);
        a += __shfl_xor(a, 2); b += __shfl_xor(b, 2);
        a += __shfl_xor(a, 4); b += __shfl_xor(b, 4);
        a += __shfl_xor(a, 8); b += __shfl_xor(b, 8);
        mean[r] = a * (1.f / 128.f);
        float var = b * (1.f / 128.f) - mean[r] * mean[r];
        rs[r] = rsqrtf(var + EPS);
    }
    #pragma unroll
    for (int t = 0; t < 8; ++t) {
        float g  = g2[t * 16 + col];
        float be = be2[t * 16 + col];
        #pragma unroll
        for (int r = 0; r < 4; ++r) {
            size_t idx = (size_t)(r0 + hg * 4 + r) * 128 + t * 16 + col;
            float x = acc[t][r];
            h1[idx] = x;
            h2[idx] = f2b((x - mean[r]) * rs[r] * g + be);
        }
    }
}

// ---------------------------------------------------------------------------
// FFN1: t = relu(h2 @ W1 + b1)
// ---------------------------------------------------------------------------
__global__ __launch_bounds__(256) void k_ffn1(
    const u16* __restrict__ h2, const u16* __restrict__ B1, const float* __restrict__ b1,
    u16* __restrict__ tb, int M)
{
    const int slab = blockIdx.x * 4 + (threadIdx.x >> 6);
    const int l = threadIdx.x & 63;
    const int r0 = slab * 16;
    if (r0 >= M) return;
    const int col = l & 15, hg = l >> 4;
    const u16* ar = h2 + (size_t)(r0 + col) * 128 + hg * 8;
    bf16x8 a0 = *(const bf16x8*)(ar);
    bf16x8 a1 = *(const bf16x8*)(ar + 32);
    bf16x8 a2 = *(const bf16x8*)(ar + 64);
    bf16x8 a3 = *(const bf16x8*)(ar + 96);
    #pragma unroll
    for (int t = 0; t < 16; ++t) {
        float bb = b1[t * 16 + col];
        f32x4 c = {bb, bb, bb, bb};
        const u16* bp = B1 + t * 2048 + l * 8;
        c = MFMA(a0, *(const bf16x8*)(bp),        c);
        c = MFMA(a1, *(const bf16x8*)(bp + 512),  c);
        c = MFMA(a2, *(const bf16x8*)(bp + 1024), c);
        c = MFMA(a3, *(const bf16x8*)(bp + 1536), c);
        #pragma unroll
        for (int r = 0; r < 4; ++r)
            tb[(size_t)(r0 + hg * 4 + r) * 256 + t * 16 + col] = f2b(fmaxf(c[r], 0.f));
    }
}

// ---------------------------------------------------------------------------
// FFN2: out = h1 + t @ W2 + b2
// ---------------------------------------------------------------------------
__global__ __launch_bounds__(256) void k_ffn2(
    const u16* __restrict__ tb, const u16* __restrict__ B2, const float* __restrict__ b2,
    const float* __restrict__ h1, float* __restrict__ out, int M)
{
    const int slab = blockIdx.x * 4 + (threadIdx.x >> 6);
    const int l = threadIdx.x & 63;
    const int r0 = slab * 16;
    if (r0 >= M) return;
    const int col = l & 15, hg = l >> 4;
    const u16* ar = tb + (size_t)(r0 + col) * 256 + hg * 8;
    bf16x8 a[8];
    #pragma unroll
    for (int i = 0; i < 8; ++i) a[i] = *(const bf16x8*)(ar + i * 32);
    #pragma unroll
    for (int t = 0; t < 8; ++t) {
        float bb = b2[t * 16 + col];
        f32x4 c = {bb, bb, bb, bb};
        const u16* bp = B2 + t * 4096 + l * 8;
        #pragma unroll
        for (int kc = 0; kc < 8; ++kc)
            c = MFMA(a[kc], *(const bf16x8*)(bp + kc * 512), c);
        #pragma unroll
        for (int r = 0; r < 4; ++r) {
            size_t idx = (size_t)(r0 + hg * 4 + r) * 128 + t * 16 + col;
            out[idx] = c[r] + h1[idx];
        }
    }
}

// ---------------------------------------------------------------------------
extern "C" void kernel_launch(void* const* d_in, const int* in_sizes, int n_in,
                              void* d_out, int out_size, void* d_ws, size_t ws_size,
                              hipStream_t stream)
{
    const float* h   = (const float*)d_in[0];
    const int*   src = (const int*)  d_in[1];
    const int*   dst = (const int*)  d_in[2];
    const float* Wq  = (const float*)d_in[3];
    const float* bq  = (const float*)d_in[4];
    const float* Wk  = (const float*)d_in[5];
    const float* bk  = (const float*)d_in[6];
    const float* Wv  = (const float*)d_in[7];
    const float* bv  = (const float*)d_in[8];
    const float* Wo  = (const float*)d_in[9];
    const float* bo  = (const float*)d_in[10];
    const float* W1  = (const float*)d_in[11];
    const float* b1  = (const float*)d_in[12];
    const float* W2  = (const float*)d_in[13];
    const float* b2  = (const float*)d_in[14];
    const float* g1  = (const float*)d_in[15];
    const float* be1 = (const float*)d_in[16];
    const float* g2  = (const float*)d_in[17];
    const float* be2 = (const float*)d_in[18];

    const int n = in_sizes[0] / HIDN;    // 100000
    const int e = in_sizes[1];           // 1600000
    float* out = (float*)d_out;

    const int nbuck = (n + 255) >> BSH;

    // --- workspace layout ---
    char* p = (char*)d_ws;
    int* csrc  = (int*)p;              p += (size_t)e * 4;
    int* cnt   = (int*)p;              p += (size_t)n * 4;
    int* offs  = (int*)p;              p += (size_t)n * 4;
    int* bcnt  = (int*)p;              p += 512 * 4;
    int* bbase = (int*)p;              p += 512 * 4;
    int* bcur  = (int*)p;              p += 512 * 4;
    u16* wpack = (u16*)p;              p += 131072 * 2;      // 256 KB packed weights
    u16* KVb  = (u16*)p;               p += (size_t)n * 256 * 2;  // 51.2 MB interleaved K|V fp16
    u16* Qh   = (u16*)p;               p += (size_t)n * 128 * 2;  // 25.6 MB Q fp16
    u16* hnew = (u16*)p;               p += (size_t)n * 128 * 2;  // 25.6 MB bf16
    float* h1 = (float*)p;             p += (size_t)n * 128 * 4;  // 51.2 MB fp32
    // aliases (lifetimes disjoint)
    u16* h2 = Qh;                      // Qh dead after k_edge
    u16* tb = KVb;                     // KVb dead after k_edge
    int2* ebuf = (int2*)h1;            // ebuf dead after k_bbuild; h1 written later

    u16* Wq_p = wpack;
    u16* Wk_p = wpack + 16384;
    u16* Wv_p = wpack + 32768;
    u16* Wo_p = wpack + 49152;
    u16* W1_p = wpack + 65536;
    u16* W2_p = wpack + 98304;

    const int nslab = (n + 15) / 16;
    const int gemm_blocks = (nslab + 3) / 4;
    const int echunks = (e + CHUNK - 1) / CHUNK;

    hipMemsetAsync(bcnt, 0, 512 * sizeof(int), stream);

    k_bcount  <<<echunks, 256, 0, stream>>>(dst, bcnt, e);
    k_bscan   <<<1, 512, 0, stream>>>(bcnt, bbase, bcur, nbuck);
    k_bscatter<<<echunks, 256, 0, stream>>>(src, dst, bcur, ebuf, e);
    k_bbuild  <<<nbuck, 256, 0, stream>>>(ebuf, bbase, cnt, offs, csrc, n);

    k_pack_all<<<64, 256, 0, stream>>>(Wq, Wk, Wv, Wo, W1, W2, wpack);

    k_qkv <<<gemm_blocks, 256, 0, stream>>>(h, g1, be1, Wq_p, Wk_p, Wv_p,
                                            bq, bk, bv, Qh, KVb, n);

    k_edge<<<(n + 3) / 4, 256, 0, stream>>>(Qh, KVb, offs, cnt, csrc, hnew, n);

    k_attnout<<<gemm_blocks, 256, 0, stream>>>(hnew, Wo_p, bo, h, g2, be2, h1, h2, n);

    k_ffn1<<<gemm_blocks, 256, 0, stream>>>(h2, W1_p, b1, tb, n);

    k_ffn2<<<gemm_blocks, 256, 0, stream>>>(tb, W2_p, b2, h1, out, n);
}

// Round 11
// 408.531 us; speedup vs baseline: 1.1882x; 1.1373x over previous
//
#include <hip/hip_runtime.h>
#include <math.h>

#define HIDN 128
#define EPS 1e-5f
#define ATT_SCALE 0.17677669529663687f   // 32^-0.5

typedef unsigned int  u32;
typedef unsigned short u16;
typedef __attribute__((ext_vector_type(8))) short bf16x8;   // 8 bf16 in 4 VGPRs
typedef __attribute__((ext_vector_type(4))) float f32x4;
typedef __attribute__((ext_vector_type(2))) float f32x2;
typedef __attribute__((ext_vector_type(2))) _Float16 h16x2;

__device__ __forceinline__ u16 f2b(float x) {           // fp32 -> bf16 RNE
    u32 u = __float_as_uint(x);
    u += 0x7FFFu + ((u >> 16) & 1u);
    return (u16)(u >> 16);
}
__device__ __forceinline__ float b2f(u16 x) { return __uint_as_float(((u32)x) << 16); }
__device__ __forceinline__ u16 f2h(float x) {           // fp32 -> fp16 RNE
    _Float16 h = (_Float16)x;
    u16 r; __builtin_memcpy(&r, &h, 2); return r;
}
__device__ __forceinline__ h16x2 u2h(u32 a) { h16x2 r; __builtin_memcpy(&r, &a, 4); return r; }

// ---- fp8 pack/unpack: HW OCP e4m3 if available, else e5m2-via-fp16 (self-consistent) ----
#if __has_builtin(__builtin_amdgcn_cvt_pk_f32_fp8) && __has_builtin(__builtin_amdgcn_cvt_pk_fp8_f32)
#define HW_FP8 1
#else
#define HW_FP8 0
#endif

__device__ __forceinline__ u32 pk_fp8(float a, float b) {   // -> 2 fp8 bytes in low u16
#if HW_FP8
    return ((u32)__builtin_amdgcn_cvt_pk_fp8_f32(a, b, 0, false)) & 0xFFFFu;
#else
    u16 ha = f2h(a), hb = f2h(b);
    u32 b0 = (((u32)ha) + 0x80u + ((ha >> 8) & 1u)) >> 8;   // e5m2 RNE truncation
    u32 b1 = (((u32)hb) + 0x80u + ((hb >> 8) & 1u)) >> 8;
    return (b0 & 0xFFu) | ((b1 & 0xFFu) << 8);
#endif
}
__device__ __forceinline__ f32x2 unpk_fp8_lo(u32 v) {
#if HW_FP8
    return __builtin_amdgcn_cvt_pk_f32_fp8(v, false);
#else
    h16x2 hh = u2h(((v & 0xFFu) << 8) | ((v & 0xFF00u) << 16));
    f32x2 r; r.x = (float)hh.x; r.y = (float)hh.y; return r;
#endif
}
__device__ __forceinline__ f32x2 unpk_fp8_hi(u32 v) {
#if HW_FP8
    return __builtin_amdgcn_cvt_pk_f32_fp8(v, true);
#else
    h16x2 hh = u2h(((v >> 16) & 0xFFu) << 8 | ((v >> 24) & 0xFFu) << 24);
    f32x2 r; r.x = (float)hh.x; r.y = (float)hh.y; return r;
#endif
}

#define MFMA(a, b, c) __builtin_amdgcn_mfma_f32_16x16x32_bf16((a), (b), (c), 0, 0, 0)

// XOR-swizzled LDS index (u16 elements, 16B granules).
__device__ __forceinline__ int swz(int row, int kpos, int rowstride) {
    return row * rowstride + ((((kpos >> 3) ^ (row & 7)) << 3) | (kpos & 7));
}

// ---------------------------------------------------------------------------
// Pack all 6 weight matrices into MFMA B-fragment order, bf16.
// ---------------------------------------------------------------------------
__global__ __launch_bounds__(256) void k_pack_all(
    const float* __restrict__ Wq, const float* __restrict__ Wk, const float* __restrict__ Wv,
    const float* __restrict__ Wo, const float* __restrict__ W1, const float* __restrict__ W2,
    u16* __restrict__ out)
{
    int idx = blockIdx.x * 256 + threadIdx.x;
    const float* W; int K, N, base, local;
    if      (idx <  2048) { W = Wq; K = 128; N = 128; base = 0;     local = idx; }
    else if (idx <  4096) { W = Wk; K = 128; N = 128; base = 16384; local = idx - 2048; }
    else if (idx <  6144) { W = Wv; K = 128; N = 128; base = 32768; local = idx - 4096; }
    else if (idx <  8192) { W = Wo; K = 128; N = 128; base = 49152; local = idx - 6144; }
    else if (idx < 12288) { W = W1; K = 128; N = 256; base = 65536; local = idx - 8192; }
    else if (idx < 16384) { W = W2; K = 256; N = 128; base = 98304; local = idx - 12288; }
    else return;
    const int KC = K >> 5;
    const int l  = local & 63;
    const int tc = local >> 6;
    const int c  = tc % KC;
    const int t  = tc / KC;
    const int col = l & 15, hg = l >> 4;
    const int kbase = c * 32 + hg * 8;
    u16 v[8];
    #pragma unroll
    for (int j = 0; j < 8; ++j) v[j] = f2b(W[(size_t)(kbase + j) * N + t * 16 + col]);
    uint4 o;
    o.x = (u32)v[0] | ((u32)v[1] << 16);
    o.y = (u32)v[2] | ((u32)v[3] << 16);
    o.z = (u32)v[4] | ((u32)v[5] << 16);
    o.w = (u32)v[6] | ((u32)v[7] << 16);
    *(uint4*)&out[base + local * 8] = o;
}

// ---------------------------------------------------------------------------
// QKV fused with LN1.  Outputs:
//   Qh : [node][128] fp16 (linear)
//   KVb: [node][128 u16] fp8 e4m3: granule g (16B) holds K[8g..8g+7] (u16 g*8+0..3)
//        and V[8g..8g+7] (u16 g*8+4..7), 2 fp8 per u16 -> one dwordx4 per lane/edge.
// ---------------------------------------------------------------------------
__global__ __launch_bounds__(256) void k_qkv(
    const float* __restrict__ h, const float* __restrict__ g1, const float* __restrict__ be1,
    const u16* __restrict__ Bq, const u16* __restrict__ Bk, const u16* __restrict__ Bv,
    const float* __restrict__ bq, const float* __restrict__ bk, const float* __restrict__ bv,
    u16* __restrict__ Qh, u16* __restrict__ KVb, int M)
{
    __shared__ u16 smem[4][2048];                 // 4 KB per wave: [16][128] u16
    const int wid = threadIdx.x >> 6;
    const int l   = threadIdx.x & 63;
    int slab = blockIdx.x * 4 + wid;
    const bool valid = (slab * 16) < M;
    if (!valid) slab = 0;
    const int r0  = slab * 16;
    const int col = l & 15, hg = l >> 4;
    u16* ws = smem[wid];

    // ---- load 32 fp32 of my row, LN stats (4 lanes/row: xor 16,32) ----
    float av[4][8];
    const float* hr = h + (size_t)(r0 + col) * 128 + hg * 8;
    #pragma unroll
    for (int c = 0; c < 4; ++c) {
        float4 p0 = *(const float4*)&hr[c * 32];
        float4 p1 = *(const float4*)&hr[c * 32 + 4];
        av[c][0] = p0.x; av[c][1] = p0.y; av[c][2] = p0.z; av[c][3] = p0.w;
        av[c][4] = p1.x; av[c][5] = p1.y; av[c][6] = p1.z; av[c][7] = p1.w;
    }
    float s = 0.f, q2 = 0.f;
    #pragma unroll
    for (int c = 0; c < 4; ++c)
        #pragma unroll
        for (int j = 0; j < 8; ++j) { float v = av[c][j]; s += v; q2 += v * v; }
    s  += __shfl_xor(s, 16);  s  += __shfl_xor(s, 32);
    q2 += __shfl_xor(q2, 16); q2 += __shfl_xor(q2, 32);
    float mean = s * (1.f / 128.f);
    float var  = q2 * (1.f / 128.f) - mean * mean;
    float rs   = rsqrtf(var + EPS);

    // ---- normalize -> bf16 A-frags ----
    bf16x8 af[4];
    #pragma unroll
    for (int c = 0; c < 4; ++c) {
        u32 w[4];
        #pragma unroll
        for (int jj = 0; jj < 4; ++jj) {
            int k0 = c * 32 + hg * 8 + 2 * jj;
            float v0 = (av[c][2 * jj]     - mean) * rs * g1[k0]     + be1[k0];
            float v1 = (av[c][2 * jj + 1] - mean) * rs * g1[k0 + 1] + be1[k0 + 1];
            w[jj] = (u32)f2b(v0) | ((u32)f2b(v1) << 16);
        }
        uint4 uu = make_uint4(w[0], w[1], w[2], w[3]);
        af[c] = *(bf16x8*)&uu;
    }

    // ---- Q GEMM -> ws (fp16) -> vector store ----
    #pragma unroll
    for (int t = 0; t < 8; ++t) {
        float bb = bq[t * 16 + col];
        f32x4 c = {bb, bb, bb, bb};
        const u16* bp = Bq + t * 2048 + l * 8;
        c = MFMA(af[0], *(const bf16x8*)(bp),        c);
        c = MFMA(af[1], *(const bf16x8*)(bp + 512),  c);
        c = MFMA(af[2], *(const bf16x8*)(bp + 1024), c);
        c = MFMA(af[3], *(const bf16x8*)(bp + 1536), c);
        #pragma unroll
        for (int r = 0; r < 4; ++r)
            ws[swz(hg * 4 + r, t * 16 + col, 128)] = f2h(c[r]);
    }
    __syncthreads();
    if (valid) {
        #pragma unroll
        for (int i = 0; i < 4; ++i) {
            int row = i * 4 + (l >> 4);
            int cg  = l & 15;
            bf16x8 vv = *(const bf16x8*)&ws[swz(row, cg * 8, 128)];
            *(bf16x8*)&Qh[(size_t)(r0 + row) * 128 + cg * 8] = vv;
        }
    }
    __syncthreads();

    // ---- K GEMM -> fp8 pairs (even-col lanes pack self+neighbor) ----
    #pragma unroll
    for (int t = 0; t < 8; ++t) {
        float bb = bk[t * 16 + col];
        f32x4 c = {bb, bb, bb, bb};
        const u16* bp = Bk + t * 2048 + l * 8;
        c = MFMA(af[0], *(const bf16x8*)(bp),        c);
        c = MFMA(af[1], *(const bf16x8*)(bp + 512),  c);
        c = MFMA(af[2], *(const bf16x8*)(bp + 1024), c);
        c = MFMA(af[3], *(const bf16x8*)(bp + 1536), c);
        int cc = t * 16 + col;
        int ki = ((cc >> 3) << 3) | ((cc & 7) >> 1);      // K pair slot
        #pragma unroll
        for (int r = 0; r < 4; ++r) {
            float other = __shfl_xor(c[r], 1);
            if ((col & 1) == 0)
                ws[swz(hg * 4 + r, ki, 128)] = (u16)pk_fp8(c[r], other);
        }
    }
    // ---- V GEMM -> fp8 pairs (disjoint u16 cells: +4 within granule) ----
    #pragma unroll
    for (int t = 0; t < 8; ++t) {
        float bb = bv[t * 16 + col];
        f32x4 c = {bb, bb, bb, bb};
        const u16* bp = Bv + t * 2048 + l * 8;
        c = MFMA(af[0], *(const bf16x8*)(bp),        c);
        c = MFMA(af[1], *(const bf16x8*)(bp + 512),  c);
        c = MFMA(af[2], *(const bf16x8*)(bp + 1024), c);
        c = MFMA(af[3], *(const bf16x8*)(bp + 1536), c);
        int cc = t * 16 + col;
        int vi = (((cc >> 3) << 3) | ((cc & 7) >> 1)) + 4; // V pair slot
        #pragma unroll
        for (int r = 0; r < 4; ++r) {
            float other = __shfl_xor(c[r], 1);
            if ((col & 1) == 0)
                ws[swz(hg * 4 + r, vi, 128)] = (u16)pk_fp8(c[r], other);
        }
    }
    __syncthreads();
    if (valid) {
        #pragma unroll
        for (int i = 0; i < 4; ++i) {
            int row = i * 4 + (l >> 4);
            int cg  = l & 15;
            bf16x8 vv = *(const bf16x8*)&ws[swz(row, cg * 8, 128)];
            *(bf16x8*)&KVb[(size_t)(r0 + row) * 128 + cg * 8] = vv;
        }
    }
}

// ---------------------------------------------------------------------------
// CSR build, two-level (bucket = 256 consecutive dst nodes).
// ---------------------------------------------------------------------------
#define BSH 8
#define CHUNK 4096

__global__ __launch_bounds__(256) void k_bcount(
    const int* __restrict__ dst, int* __restrict__ bcnt, int e)
{
    __shared__ int hist[512];
    const int tid = threadIdx.x;
    hist[tid] = 0; hist[tid + 256] = 0;
    __syncthreads();
    const int i0 = blockIdx.x * CHUNK;
    #pragma unroll
    for (int t = 0; t < CHUNK / 256; ++t) {
        int i = i0 + t * 256 + tid;
        if (i < e) atomicAdd(&hist[dst[i] >> BSH], 1);
    }
    __syncthreads();
    for (int j = tid; j < 512; j += 256) {
        int c = hist[j];
        if (c) atomicAdd(&bcnt[j], c);
    }
}

__global__ __launch_bounds__(512) void k_bscan(
    const int* __restrict__ bcnt, int* __restrict__ bbase, int* __restrict__ bcur, int nbuck)
{
    __shared__ int ts[512];
    const int tid = threadIdx.x;
    int v = (tid < nbuck) ? bcnt[tid] : 0;
    ts[tid] = v;
    __syncthreads();
    for (int off = 1; off < 512; off <<= 1) {
        int x = (tid >= off) ? ts[tid - off] : 0;
        __syncthreads();
        ts[tid] += x;
        __syncthreads();
    }
    int ex = ts[tid] - v;
    if (tid <= nbuck) bbase[tid] = ex;
    if (tid < nbuck)  bcur[tid]  = ex;
}

__global__ __launch_bounds__(256) void k_bscatter(
    const int* __restrict__ src, const int* __restrict__ dst,
    int* __restrict__ bcur, int2* __restrict__ ebuf, int e)
{
    __shared__ int hist[512];
    __shared__ int lbase[512];
    __shared__ int lrun[512];
    const int tid = threadIdx.x;
    hist[tid] = 0; hist[tid + 256] = 0;
    __syncthreads();
    const int i0 = blockIdx.x * CHUNK;
    #pragma unroll
    for (int t = 0; t < CHUNK / 256; ++t) {
        int i = i0 + t * 256 + tid;
        if (i < e) atomicAdd(&hist[dst[i] >> BSH], 1);
    }
    __syncthreads();
    for (int j = tid; j < 512; j += 256) {
        int c = hist[j];
        lrun[j] = 0;
        if (c) lbase[j] = atomicAdd(&bcur[j], c);
    }
    __syncthreads();
    #pragma unroll
    for (int t = 0; t < CHUNK / 256; ++t) {
        int i = i0 + t * 256 + tid;
        if (i < e) {
            int d = dst[i];
            int b = d >> BSH;
            int r = atomicAdd(&lrun[b], 1);
            ebuf[lbase[b] + r] = make_int2(src[i], d);
        }
    }
}

__global__ __launch_bounds__(256) void k_bbuild(
    const int2* __restrict__ ebuf, const int* __restrict__ bbase,
    int* __restrict__ cnt, int* __restrict__ offs, int* __restrict__ csrc, int n)
{
    __shared__ int ncnt[256];
    __shared__ int ts[256];
    __shared__ int nrun[256];
    const int tid = threadIdx.x;
    const int b = blockIdx.x;
    const int node0 = b << BSH;
    const int nn = min(256, n - node0);
    const int s = bbase[b];
    const int epb = bbase[b + 1] - s;

    ncnt[tid] = 0;
    __syncthreads();
    for (int i = tid; i < epb; i += 256)
        atomicAdd(&ncnt[ebuf[s + i].y & 255], 1);
    __syncthreads();
    int v = ncnt[tid];
    ts[tid] = v;
    __syncthreads();
    for (int off = 1; off < 256; off <<= 1) {
        int x = (tid >= off) ? ts[tid - off] : 0;
        __syncthreads();
        ts[tid] += x;
        __syncthreads();
    }
    int ex = ts[tid] - v;
    if (tid < nn) { cnt[node0 + tid] = v; offs[node0 + tid] = s + ex; }
    nrun[tid] = 0;
    __syncthreads();
    ncnt[tid] = ex;
    __syncthreads();
    for (int i = tid; i < epb; i += 256) {
        int2 p = ebuf[s + i];
        int d = p.y & 255;
        int r = atomicAdd(&nrun[d], 1);
        csrc[s + ncnt[d] + r] = p.x;
    }
}

// ---------------------------------------------------------------------------
// Edge attention, 4 edge-slots/wave (16 lanes/edge, 8 dims/lane).
// fp8 KV: ONE dwordx4 per lane per edge (K 8 dims + V 8 dims in 16B).
// Single pass (scores O(1); softmax shift-invariant).
// ---------------------------------------------------------------------------
__global__ __launch_bounds__(256) void k_edge(
    const u16* __restrict__ Qh, const u16* __restrict__ KVb,
    const int* __restrict__ offs, const int* __restrict__ cnt, const int* __restrict__ csrc,
    u16* __restrict__ hnew, int n)
{
    const int wid  = threadIdx.x >> 6;
    const int l    = threadIdx.x & 63;
    const int node = blockIdx.x * 4 + wid;
    if (node >= n) return;
    const int start = offs[node];
    const int deg   = cnt[node];
    const int w    = l & 15;       // dims 8w..8w+7 (head = w>>2)
    const int slot = l >> 4;       // edge slot 0..3

    const uint4 q = *(const uint4*)&Qh[(size_t)node * 128 + w * 8];
    float qf[8];
    { h16x2 t;
      t = u2h(q.x); qf[0] = (float)t.x; qf[1] = (float)t.y;
      t = u2h(q.y); qf[2] = (float)t.x; qf[3] = (float)t.y;
      t = u2h(q.z); qf[4] = (float)t.x; qf[5] = (float)t.y;
      t = u2h(q.w); qf[6] = (float)t.x; qf[7] = (float)t.y; }

    float of[8] = {0, 0, 0, 0, 0, 0, 0, 0};
    float denom = 0.f;

    for (int base = 0; base < deg; base += 64) {
        int m = deg - base; if (m > 64) m = 64;
        int myidx = 0;
        if (l < m) myidx = csrc[start + base + l];
        for (int j = 0; j < m; j += 4) {
            int eloc = j + slot;
            int s = __shfl(myidx, eloc & 63);
            const uint4 kv = *(const uint4*)&KVb[(size_t)s * 128 + w * 8];
            f32x2 k01 = unpk_fp8_lo(kv.x), k23 = unpk_fp8_hi(kv.x);
            f32x2 k45 = unpk_fp8_lo(kv.y), k67 = unpk_fp8_hi(kv.y);
            float p;
            p = qf[0] * k01.x;
            p = fmaf(qf[1], k01.y, p);
            p = fmaf(qf[2], k23.x, p);
            p = fmaf(qf[3], k23.y, p);
            p = fmaf(qf[4], k45.x, p);
            p = fmaf(qf[5], k45.y, p);
            p = fmaf(qf[6], k67.x, p);
            p = fmaf(qf[7], k67.y, p);
            p += __shfl_xor(p, 1);
            p += __shfl_xor(p, 2);
            float al = __expf(p * ATT_SCALE);
            al = (eloc < m) ? al : 0.f;
            denom += al;
            f32x2 v01 = unpk_fp8_lo(kv.z), v23 = unpk_fp8_hi(kv.z);
            f32x2 v45 = unpk_fp8_lo(kv.w), v67 = unpk_fp8_hi(kv.w);
            of[0] = fmaf(al, v01.x, of[0]);
            of[1] = fmaf(al, v01.y, of[1]);
            of[2] = fmaf(al, v23.x, of[2]);
            of[3] = fmaf(al, v23.y, of[3]);
            of[4] = fmaf(al, v45.x, of[4]);
            of[5] = fmaf(al, v45.y, of[5]);
            of[6] = fmaf(al, v67.x, of[6]);
            of[7] = fmaf(al, v67.y, of[7]);
        }
    }

    // cross-slot reduce (lanes l, l^16, l^32 hold same dims)
    #pragma unroll
    for (int msk = 16; msk <= 32; msk <<= 1) {
        #pragma unroll
        for (int i = 0; i < 8; ++i) of[i] += __shfl_xor(of[i], msk);
        denom += __shfl_xor(denom, msk);
    }
    float inv = (deg > 0) ? (1.f / denom) : 0.f;
    if (slot == 0) {
        u32 wrd[4];
        #pragma unroll
        for (int i = 0; i < 4; ++i)
            wrd[i] = (u32)f2b(of[2 * i] * inv) | ((u32)f2b(of[2 * i + 1] * inv) << 16);
        uint4 uu = make_uint4(wrd[0], wrd[1], wrd[2], wrd[3]);
        *(uint4*)&hnew[(size_t)node * 128 + w * 8] = uu;
    }
}

// ---------------------------------------------------------------------------
// Attn-out + residual + LN2: h1 fp32, h2 bf16.
// ---------------------------------------------------------------------------
__global__ __launch_bounds__(256) void k_attnout(
    const u16* __restrict__ hnew, const u16* __restrict__ Bo, const float* __restrict__ bo,
    const float* __restrict__ h, const float* __restrict__ g2, const float* __restrict__ be2,
    float* __restrict__ h1, u16* __restrict__ h2, int M)
{
    const int slab = blockIdx.x * 4 + (threadIdx.x >> 6);
    const int l = threadIdx.x & 63;
    const int r0 = slab * 16;
    if (r0 >= M) return;
    const int col = l & 15, hg = l >> 4;
    const u16* ar = hnew + (size_t)(r0 + col) * 128 + hg * 8;
    bf16x8 a0 = *(const bf16x8*)(ar);
    bf16x8 a1 = *(const bf16x8*)(ar + 32);
    bf16x8 a2 = *(const bf16x8*)(ar + 64);
    bf16x8 a3 = *(const bf16x8*)(ar + 96);
    f32x4 acc[8];
    #pragma unroll
    for (int t = 0; t < 8; ++t) {
        float bb = bo[t * 16 + col];
        f32x4 c = {bb, bb, bb, bb};
        const u16* bp = Bo + t * 2048 + l * 8;
        c = MFMA(a0, *(const bf16x8*)(bp),        c);
        c = MFMA(a1, *(const bf16x8*)(bp + 512),  c);
        c = MFMA(a2, *(const bf16x8*)(bp + 1024), c);
        c = MFMA(a3, *(const bf16x8*)(bp + 1536), c);
        acc[t] = c;
    }
    float s[4] = {0, 0, 0, 0}, s2[4] = {0, 0, 0, 0};
    #pragma unroll
    for (int t = 0; t < 8; ++t) {
        #pragma unroll
        for (int r = 0; r < 4; ++r) {
            float x = acc[t][r] + h[(size_t)(r0 + hg * 4 + r) * 128 + t * 16 + col];
            acc[t][r] = x;
            s[r] += x; s2[r] += x * x;
        }
    }
    float mean[4], rs[4];
    #pragma unroll
    for (int r = 0; r < 4; ++r) {
        float a = s[r], b = s2[r];
        a += __shfl_xor(a, 1); b += __shfl_xor(b, 1);
        a += __shfl_xor(a, 2); b += __shfl_xor(b, 2);
        a += __shfl_xor(a, 4); b += __shfl_xor(b, 4);
        a += __shfl_xor(a, 8); b += __shfl_xor(b, 8);
        mean[r] = a * (1.f / 128.f);
        float var = b * (1.f / 128.f) - mean[r] * mean[r];
        rs[r] = rsqrtf(var + EPS);
    }
    #pragma unroll
    for (int t = 0; t < 8; ++t) {
        float g  = g2[t * 16 + col];
        float be = be2[t * 16 + col];
        #pragma unroll
        for (int r = 0; r < 4; ++r) {
            size_t idx = (size_t)(r0 + hg * 4 + r) * 128 + t * 16 + col;
            float x = acc[t][r];
            h1[idx] = x;
            h2[idx] = f2b((x - mean[r]) * rs[r] * g + be);
        }
    }
}

// ---------------------------------------------------------------------------
// FFN1: t = relu(h2 @ W1 + b1)
// ---------------------------------------------------------------------------
__global__ __launch_bounds__(256) void k_ffn1(
    const u16* __restrict__ h2, const u16* __restrict__ B1, const float* __restrict__ b1,
    u16* __restrict__ tb, int M)
{
    const int slab = blockIdx.x * 4 + (threadIdx.x >> 6);
    const int l = threadIdx.x & 63;
    const int r0 = slab * 16;
    if (r0 >= M) return;
    const int col = l & 15, hg = l >> 4;
    const u16* ar = h2 + (size_t)(r0 + col) * 128 + hg * 8;
    bf16x8 a0 = *(const bf16x8*)(ar);
    bf16x8 a1 = *(const bf16x8*)(ar + 32);
    bf16x8 a2 = *(const bf16x8*)(ar + 64);
    bf16x8 a3 = *(const bf16x8*)(ar + 96);
    #pragma unroll
    for (int t = 0; t < 16; ++t) {
        float bb = b1[t * 16 + col];
        f32x4 c = {bb, bb, bb, bb};
        const u16* bp = B1 + t * 2048 + l * 8;
        c = MFMA(a0, *(const bf16x8*)(bp),        c);
        c = MFMA(a1, *(const bf16x8*)(bp + 512),  c);
        c = MFMA(a2, *(const bf16x8*)(bp + 1024), c);
        c = MFMA(a3, *(const bf16x8*)(bp + 1536), c);
        #pragma unroll
        for (int r = 0; r < 4; ++r)
            tb[(size_t)(r0 + hg * 4 + r) * 256 + t * 16 + col] = f2b(fmaxf(c[r], 0.f));
    }
}

// ---------------------------------------------------------------------------
// FFN2: out = h1 + t @ W2 + b2
// ---------------------------------------------------------------------------
__global__ __launch_bounds__(256) void k_ffn2(
    const u16* __restrict__ tb, const u16* __restrict__ B2, const float* __restrict__ b2,
    const float* __restrict__ h1, float* __restrict__ out, int M)
{
    const int slab = blockIdx.x * 4 + (threadIdx.x >> 6);
    const int l = threadIdx.x & 63;
    const int r0 = slab * 16;
    if (r0 >= M) return;
    const int col = l & 15, hg = l >> 4;
    const u16* ar = tb + (size_t)(r0 + col) * 256 + hg * 8;
    bf16x8 a[8];
    #pragma unroll
    for (int i = 0; i < 8; ++i) a[i] = *(const bf16x8*)(ar + i * 32);
    #pragma unroll
    for (int t = 0; t < 8; ++t) {
        float bb = b2[t * 16 + col];
        f32x4 c = {bb, bb, bb, bb};
        const u16* bp = B2 + t * 4096 + l * 8;
        #pragma unroll
        for (int kc = 0; kc < 8; ++kc)
            c = MFMA(a[kc], *(const bf16x8*)(bp + kc * 512), c);
        #pragma unroll
        for (int r = 0; r < 4; ++r) {
            size_t idx = (size_t)(r0 + hg * 4 + r) * 128 + t * 16 + col;
            out[idx] = c[r] + h1[idx];
        }
    }
}

// ---------------------------------------------------------------------------
extern "C" void kernel_launch(void* const* d_in, const int* in_sizes, int n_in,
                              void* d_out, int out_size, void* d_ws, size_t ws_size,
                              hipStream_t stream)
{
    const float* h   = (const float*)d_in[0];
    const int*   src = (const int*)  d_in[1];
    const int*   dst = (const int*)  d_in[2];
    const float* Wq  = (const float*)d_in[3];
    const float* bq  = (const float*)d_in[4];
    const float* Wk  = (const float*)d_in[5];
    const float* bk  = (const float*)d_in[6];
    const float* Wv  = (const float*)d_in[7];
    const float* bv  = (const float*)d_in[8];
    const float* Wo  = (const float*)d_in[9];
    const float* bo  = (const float*)d_in[10];
    const float* W1  = (const float*)d_in[11];
    const float* b1  = (const float*)d_in[12];
    const float* W2  = (const float*)d_in[13];
    const float* b2  = (const float*)d_in[14];
    const float* g1  = (const float*)d_in[15];
    const float* be1 = (const float*)d_in[16];
    const float* g2  = (const float*)d_in[17];
    const float* be2 = (const float*)d_in[18];

    const int n = in_sizes[0] / HIDN;    // 100000
    const int e = in_sizes[1];           // 1600000
    float* out = (float*)d_out;

    const int nbuck = (n + 255) >> BSH;

    // --- workspace layout ---
    char* p = (char*)d_ws;
    int* csrc  = (int*)p;              p += (size_t)e * 4;
    int* cnt   = (int*)p;              p += (size_t)n * 4;
    int* offs  = (int*)p;              p += (size_t)n * 4;
    int* bcnt  = (int*)p;              p += 512 * 4;
    int* bbase = (int*)p;              p += 512 * 4;
    int* bcur  = (int*)p;              p += 512 * 4;
    u16* wpack = (u16*)p;              p += 131072 * 2;          // 256 KB packed weights
    u16* KVb  = (u16*)p;               p += (size_t)n * 128 * 2; // 25.6 MB fp8-packed K|V
    u16* Qh   = (u16*)p;               p += (size_t)n * 128 * 2; // 25.6 MB Q fp16
    u16* hnew = (u16*)p;               p += (size_t)n * 128 * 2; // 25.6 MB bf16
    float* h1 = (float*)p;             p += (size_t)n * 128 * 4; // 51.2 MB fp32
    u16* tb   = (u16*)p;               p += (size_t)n * 256 * 2; // 51.2 MB bf16 FFN mid
    // aliases (lifetimes disjoint)
    u16* h2 = Qh;                      // Qh dead after k_edge
    int2* ebuf = (int2*)h1;            // ebuf dead after k_bbuild; h1 written later

    u16* Wq_p = wpack;
    u16* Wk_p = wpack + 16384;
    u16* Wv_p = wpack + 32768;
    u16* Wo_p = wpack + 49152;
    u16* W1_p = wpack + 65536;
    u16* W2_p = wpack + 98304;

    const int nslab = (n + 15) / 16;
    const int gemm_blocks = (nslab + 3) / 4;
    const int echunks = (e + CHUNK - 1) / CHUNK;

    hipMemsetAsync(bcnt, 0, 512 * sizeof(int), stream);

    k_bcount  <<<echunks, 256, 0, stream>>>(dst, bcnt, e);
    k_bscan   <<<1, 512, 0, stream>>>(bcnt, bbase, bcur, nbuck);
    k_bscatter<<<echunks, 256, 0, stream>>>(src, dst, bcur, ebuf, e);
    k_bbuild  <<<nbuck, 256, 0, stream>>>(ebuf, bbase, cnt, offs, csrc, n);

    k_pack_all<<<64, 256, 0, stream>>>(Wq, Wk, Wv, Wo, W1, W2, wpack);

    k_qkv <<<gemm_blocks, 256, 0, stream>>>(h, g1, be1, Wq_p, Wk_p, Wv_p,
                                            bq, bk, bv, Qh, KVb, n);

    k_edge<<<(n + 3) / 4, 256, 0, stream>>>(Qh, KVb, offs, cnt, csrc, hnew, n);

    k_attnout<<<gemm_blocks, 256, 0, stream>>>(hnew, Wo_p, bo, h, g2, be2, h1, h2, n);

    k_ffn1<<<gemm_blocks, 256, 0, stream>>>(h2, W1_p, b1, tb, n);

    k_ffn2<<<gemm_blocks, 256, 0, stream>>>(tb, W2_p, b2, h1, out, n);
}

// Round 12
// 395.237 us; speedup vs baseline: 1.2282x; 1.0336x over previous
//
#include <hip/hip_runtime.h>
#include <math.h>

#define HIDN 128
#define EPS 1e-5f
#define ATT_SCALE 0.17677669529663687f   // 32^-0.5

typedef unsigned int  u32;
typedef unsigned short u16;
typedef __attribute__((ext_vector_type(8))) short bf16x8;   // 8 bf16 in 4 VGPRs
typedef __attribute__((ext_vector_type(4))) float f32x4;
typedef __attribute__((ext_vector_type(2))) float f32x2;
typedef __attribute__((ext_vector_type(2))) _Float16 h16x2;

__device__ __forceinline__ u16 f2b(float x) {           // fp32 -> bf16 RNE
    u32 u = __float_as_uint(x);
    u += 0x7FFFu + ((u >> 16) & 1u);
    return (u16)(u >> 16);
}
__device__ __forceinline__ float b2f(u16 x) { return __uint_as_float(((u32)x) << 16); }
__device__ __forceinline__ u16 f2h(float x) {           // fp32 -> fp16 RNE
    _Float16 h = (_Float16)x;
    u16 r; __builtin_memcpy(&r, &h, 2); return r;
}
__device__ __forceinline__ h16x2 u2h(u32 a) { h16x2 r; __builtin_memcpy(&r, &a, 4); return r; }

// ---- fp8 pack/unpack: HW OCP e4m3 if available, else e5m2-via-fp16 (self-consistent) ----
#if __has_builtin(__builtin_amdgcn_cvt_pk_f32_fp8) && __has_builtin(__builtin_amdgcn_cvt_pk_fp8_f32)
#define HW_FP8 1
#else
#define HW_FP8 0
#endif

__device__ __forceinline__ u32 pk_fp8(float a, float b) {   // -> 2 fp8 bytes in low u16
#if HW_FP8
    return ((u32)__builtin_amdgcn_cvt_pk_fp8_f32(a, b, 0, false)) & 0xFFFFu;
#else
    u16 ha = f2h(a), hb = f2h(b);
    u32 b0 = (((u32)ha) + 0x80u + ((ha >> 8) & 1u)) >> 8;   // e5m2 RNE truncation
    u32 b1 = (((u32)hb) + 0x80u + ((hb >> 8) & 1u)) >> 8;
    return (b0 & 0xFFu) | ((b1 & 0xFFu) << 8);
#endif
}
__device__ __forceinline__ f32x2 unpk_fp8_lo(u32 v) {
#if HW_FP8
    return __builtin_amdgcn_cvt_pk_f32_fp8(v, false);
#else
    h16x2 hh = u2h(((v & 0xFFu) << 8) | ((v & 0xFF00u) << 16));
    f32x2 r; r.x = (float)hh.x; r.y = (float)hh.y; return r;
#endif
}
__device__ __forceinline__ f32x2 unpk_fp8_hi(u32 v) {
#if HW_FP8
    return __builtin_amdgcn_cvt_pk_f32_fp8(v, true);
#else
    h16x2 hh = u2h(((v >> 16) & 0xFFu) << 8 | ((v >> 24) & 0xFFu) << 24);
    f32x2 r; r.x = (float)hh.x; r.y = (float)hh.y; return r;
#endif
}

#define MFMA(a, b, c) __builtin_amdgcn_mfma_f32_16x16x32_bf16((a), (b), (c), 0, 0, 0)

// XOR-swizzled LDS index (u16 elements, 16B granules).
__device__ __forceinline__ int swz(int row, int kpos, int rowstride) {
    return row * rowstride + ((((kpos >> 3) ^ (row & 7)) << 3) | (kpos & 7));
}

// ---------------------------------------------------------------------------
// Pack all 6 weight matrices into MFMA B-fragment order, bf16.
// ---------------------------------------------------------------------------
__global__ __launch_bounds__(256) void k_pack_all(
    const float* __restrict__ Wq, const float* __restrict__ Wk, const float* __restrict__ Wv,
    const float* __restrict__ Wo, const float* __restrict__ W1, const float* __restrict__ W2,
    u16* __restrict__ out)
{
    int idx = blockIdx.x * 256 + threadIdx.x;
    const float* W; int K, N, base, local;
    if      (idx <  2048) { W = Wq; K = 128; N = 128; base = 0;     local = idx; }
    else if (idx <  4096) { W = Wk; K = 128; N = 128; base = 16384; local = idx - 2048; }
    else if (idx <  6144) { W = Wv; K = 128; N = 128; base = 32768; local = idx - 4096; }
    else if (idx <  8192) { W = Wo; K = 128; N = 128; base = 49152; local = idx - 6144; }
    else if (idx < 12288) { W = W1; K = 128; N = 256; base = 65536; local = idx - 8192; }
    else if (idx < 16384) { W = W2; K = 256; N = 128; base = 98304; local = idx - 12288; }
    else return;
    const int KC = K >> 5;
    const int l  = local & 63;
    const int tc = local >> 6;
    const int c  = tc % KC;
    const int t  = tc / KC;
    const int col = l & 15, hg = l >> 4;
    const int kbase = c * 32 + hg * 8;
    u16 v[8];
    #pragma unroll
    for (int j = 0; j < 8; ++j) v[j] = f2b(W[(size_t)(kbase + j) * N + t * 16 + col]);
    uint4 o;
    o.x = (u32)v[0] | ((u32)v[1] << 16);
    o.y = (u32)v[2] | ((u32)v[3] << 16);
    o.z = (u32)v[4] | ((u32)v[5] << 16);
    o.w = (u32)v[6] | ((u32)v[7] << 16);
    *(uint4*)&out[base + local * 8] = o;
}

// ---------------------------------------------------------------------------
// QKV fused with LN1.  Outputs:
//   Qh : [node][128] fp16 (linear)
//   KVb: [node][128 u16] fp8: granule g (16B) holds K[8g..8g+7] (u16 g*8+0..3)
//        and V[8g..8g+7] (u16 g*8+4..7), 2 fp8 per u16 -> one dwordx4 per lane/edge.
// ---------------------------------------------------------------------------
__global__ __launch_bounds__(256) void k_qkv(
    const float* __restrict__ h, const float* __restrict__ g1, const float* __restrict__ be1,
    const u16* __restrict__ Bq, const u16* __restrict__ Bk, const u16* __restrict__ Bv,
    const float* __restrict__ bq, const float* __restrict__ bk, const float* __restrict__ bv,
    u16* __restrict__ Qh, u16* __restrict__ KVb, int M)
{
    __shared__ u16 smem[4][2048];                 // 4 KB per wave: [16][128] u16
    const int wid = threadIdx.x >> 6;
    const int l   = threadIdx.x & 63;
    int slab = blockIdx.x * 4 + wid;
    const bool valid = (slab * 16) < M;
    if (!valid) slab = 0;
    const int r0  = slab * 16;
    const int col = l & 15, hg = l >> 4;
    u16* ws = smem[wid];

    // ---- load 32 fp32 of my row, LN stats (4 lanes/row: xor 16,32) ----
    float av[4][8];
    const float* hr = h + (size_t)(r0 + col) * 128 + hg * 8;
    #pragma unroll
    for (int c = 0; c < 4; ++c) {
        float4 p0 = *(const float4*)&hr[c * 32];
        float4 p1 = *(const float4*)&hr[c * 32 + 4];
        av[c][0] = p0.x; av[c][1] = p0.y; av[c][2] = p0.z; av[c][3] = p0.w;
        av[c][4] = p1.x; av[c][5] = p1.y; av[c][6] = p1.z; av[c][7] = p1.w;
    }
    float s = 0.f, q2 = 0.f;
    #pragma unroll
    for (int c = 0; c < 4; ++c)
        #pragma unroll
        for (int j = 0; j < 8; ++j) { float v = av[c][j]; s += v; q2 += v * v; }
    s  += __shfl_xor(s, 16);  s  += __shfl_xor(s, 32);
    q2 += __shfl_xor(q2, 16); q2 += __shfl_xor(q2, 32);
    float mean = s * (1.f / 128.f);
    float var  = q2 * (1.f / 128.f) - mean * mean;
    float rs   = rsqrtf(var + EPS);

    // ---- normalize -> bf16 A-frags ----
    bf16x8 af[4];
    #pragma unroll
    for (int c = 0; c < 4; ++c) {
        u32 w[4];
        #pragma unroll
        for (int jj = 0; jj < 4; ++jj) {
            int k0 = c * 32 + hg * 8 + 2 * jj;
            float v0 = (av[c][2 * jj]     - mean) * rs * g1[k0]     + be1[k0];
            float v1 = (av[c][2 * jj + 1] - mean) * rs * g1[k0 + 1] + be1[k0 + 1];
            w[jj] = (u32)f2b(v0) | ((u32)f2b(v1) << 16);
        }
        uint4 uu = make_uint4(w[0], w[1], w[2], w[3]);
        af[c] = *(bf16x8*)&uu;
    }

    // ---- Q GEMM -> ws (fp16) -> vector store ----
    #pragma unroll
    for (int t = 0; t < 8; ++t) {
        float bb = bq[t * 16 + col];
        f32x4 c = {bb, bb, bb, bb};
        const u16* bp = Bq + t * 2048 + l * 8;
        c = MFMA(af[0], *(const bf16x8*)(bp),        c);
        c = MFMA(af[1], *(const bf16x8*)(bp + 512),  c);
        c = MFMA(af[2], *(const bf16x8*)(bp + 1024), c);
        c = MFMA(af[3], *(const bf16x8*)(bp + 1536), c);
        #pragma unroll
        for (int r = 0; r < 4; ++r)
            ws[swz(hg * 4 + r, t * 16 + col, 128)] = f2h(c[r]);
    }
    __syncthreads();
    if (valid) {
        #pragma unroll
        for (int i = 0; i < 4; ++i) {
            int row = i * 4 + (l >> 4);
            int cg  = l & 15;
            bf16x8 vv = *(const bf16x8*)&ws[swz(row, cg * 8, 128)];
            *(bf16x8*)&Qh[(size_t)(r0 + row) * 128 + cg * 8] = vv;
        }
    }
    __syncthreads();

    // ---- K GEMM -> fp8 pairs (even-col lanes pack self+neighbor) ----
    #pragma unroll
    for (int t = 0; t < 8; ++t) {
        float bb = bk[t * 16 + col];
        f32x4 c = {bb, bb, bb, bb};
        const u16* bp = Bk + t * 2048 + l * 8;
        c = MFMA(af[0], *(const bf16x8*)(bp),        c);
        c = MFMA(af[1], *(const bf16x8*)(bp + 512),  c);
        c = MFMA(af[2], *(const bf16x8*)(bp + 1024), c);
        c = MFMA(af[3], *(const bf16x8*)(bp + 1536), c);
        int cc = t * 16 + col;
        int ki = ((cc >> 3) << 3) | ((cc & 7) >> 1);      // K pair slot
        #pragma unroll
        for (int r = 0; r < 4; ++r) {
            float other = __shfl_xor(c[r], 1);
            if ((col & 1) == 0)
                ws[swz(hg * 4 + r, ki, 128)] = (u16)pk_fp8(c[r], other);
        }
    }
    // ---- V GEMM -> fp8 pairs (disjoint u16 cells: +4 within granule) ----
    #pragma unroll
    for (int t = 0; t < 8; ++t) {
        float bb = bv[t * 16 + col];
        f32x4 c = {bb, bb, bb, bb};
        const u16* bp = Bv + t * 2048 + l * 8;
        c = MFMA(af[0], *(const bf16x8*)(bp),        c);
        c = MFMA(af[1], *(const bf16x8*)(bp + 512),  c);
        c = MFMA(af[2], *(const bf16x8*)(bp + 1024), c);
        c = MFMA(af[3], *(const bf16x8*)(bp + 1536), c);
        int cc = t * 16 + col;
        int vi = (((cc >> 3) << 3) | ((cc & 7) >> 1)) + 4; // V pair slot
        #pragma unroll
        for (int r = 0; r < 4; ++r) {
            float other = __shfl_xor(c[r], 1);
            if ((col & 1) == 0)
                ws[swz(hg * 4 + r, vi, 128)] = (u16)pk_fp8(c[r], other);
        }
    }
    __syncthreads();
    if (valid) {
        #pragma unroll
        for (int i = 0; i < 4; ++i) {
            int row = i * 4 + (l >> 4);
            int cg  = l & 15;
            bf16x8 vv = *(const bf16x8*)&ws[swz(row, cg * 8, 128)];
            *(bf16x8*)&KVb[(size_t)(r0 + row) * 128 + cg * 8] = vv;
        }
    }
}

// ---------------------------------------------------------------------------
// CSR build, two-level (bucket = 256 consecutive dst nodes).
// ebuf entry packed u32: src (low 24 bits) | (dst&255)<<24  (valid for n<2^24)
// ---------------------------------------------------------------------------
#define BSH 8
#define CHUNK 4096

__global__ __launch_bounds__(256) void k_bcount(
    const int* __restrict__ dst, int* __restrict__ bcnt, int e)
{
    __shared__ int hist[512];
    const int tid = threadIdx.x;
    hist[tid] = 0; hist[tid + 256] = 0;
    __syncthreads();
    const int i0 = blockIdx.x * CHUNK;
    #pragma unroll
    for (int t = 0; t < CHUNK / 256; ++t) {
        int i = i0 + t * 256 + tid;
        if (i < e) atomicAdd(&hist[dst[i] >> BSH], 1);
    }
    __syncthreads();
    for (int j = tid; j < 512; j += 256) {
        int c = hist[j];
        if (c) atomicAdd(&bcnt[j], c);
    }
}

__global__ __launch_bounds__(512) void k_bscan(
    const int* __restrict__ bcnt, int* __restrict__ bbase, int* __restrict__ bcur, int nbuck)
{
    __shared__ int ts[512];
    const int tid = threadIdx.x;
    int v = (tid < nbuck) ? bcnt[tid] : 0;
    ts[tid] = v;
    __syncthreads();
    for (int off = 1; off < 512; off <<= 1) {
        int x = (tid >= off) ? ts[tid - off] : 0;
        __syncthreads();
        ts[tid] += x;
        __syncthreads();
    }
    int ex = ts[tid] - v;
    if (tid <= nbuck) bbase[tid] = ex;
    if (tid < nbuck)  bcur[tid]  = ex;
}

__global__ __launch_bounds__(256) void k_bscatter(
    const int* __restrict__ src, const int* __restrict__ dst,
    int* __restrict__ bcur, u32* __restrict__ ebuf, int e)
{
    __shared__ int hist[512];
    __shared__ int lbase[512];
    __shared__ int lrun[512];
    const int tid = threadIdx.x;
    hist[tid] = 0; hist[tid + 256] = 0;
    __syncthreads();
    const int i0 = blockIdx.x * CHUNK;
    #pragma unroll
    for (int t = 0; t < CHUNK / 256; ++t) {
        int i = i0 + t * 256 + tid;
        if (i < e) atomicAdd(&hist[dst[i] >> BSH], 1);
    }
    __syncthreads();
    for (int j = tid; j < 512; j += 256) {
        int c = hist[j];
        lrun[j] = 0;
        if (c) lbase[j] = atomicAdd(&bcur[j], c);
    }
    __syncthreads();
    #pragma unroll
    for (int t = 0; t < CHUNK / 256; ++t) {
        int i = i0 + t * 256 + tid;
        if (i < e) {
            int d = dst[i];
            int b = d >> BSH;
            int r = atomicAdd(&lrun[b], 1);
            ebuf[lbase[b] + r] = (u32)src[i] | ((u32)(d & 255) << 24);
        }
    }
}

__global__ __launch_bounds__(256) void k_bbuild(
    const u32* __restrict__ ebuf, const int* __restrict__ bbase,
    int* __restrict__ cnt, int* __restrict__ offs, int* __restrict__ csrc, int n)
{
    __shared__ int ncnt[256];
    __shared__ int ts[256];
    __shared__ int nrun[256];
    const int tid = threadIdx.x;
    const int b = blockIdx.x;
    const int node0 = b << BSH;
    const int nn = min(256, n - node0);
    const int s = bbase[b];
    const int epb = bbase[b + 1] - s;

    ncnt[tid] = 0;
    __syncthreads();
    for (int i = tid; i < epb; i += 256)
        atomicAdd(&ncnt[ebuf[s + i] >> 24], 1);
    __syncthreads();
    int v = ncnt[tid];
    ts[tid] = v;
    __syncthreads();
    for (int off = 1; off < 256; off <<= 1) {
        int x = (tid >= off) ? ts[tid - off] : 0;
        __syncthreads();
        ts[tid] += x;
        __syncthreads();
    }
    int ex = ts[tid] - v;
    if (tid < nn) { cnt[node0 + tid] = v; offs[node0 + tid] = s + ex; }
    nrun[tid] = 0;
    __syncthreads();
    ncnt[tid] = ex;
    __syncthreads();
    for (int i = tid; i < epb; i += 256) {
        u32 p = ebuf[s + i];
        int d = p >> 24;
        int r = atomicAdd(&nrun[d], 1);
        csrc[s + ncnt[d] + r] = (int)(p & 0xFFFFFFu);
    }
}

// ---------------------------------------------------------------------------
// Edge attention, 4 edge-slots/wave (16 lanes/edge, 8 dims/lane).
// fp8 KV: ONE dwordx4 per lane per edge (K 8 dims + V 8 dims in 16B).
// Single pass (scores O(1); softmax shift-invariant).
// ---------------------------------------------------------------------------
__global__ __launch_bounds__(256) void k_edge(
    const u16* __restrict__ Qh, const u16* __restrict__ KVb,
    const int* __restrict__ offs, const int* __restrict__ cnt, const int* __restrict__ csrc,
    u16* __restrict__ hnew, int n)
{
    const int wid  = threadIdx.x >> 6;
    const int l    = threadIdx.x & 63;
    const int node = blockIdx.x * 4 + wid;
    if (node >= n) return;
    const int start = offs[node];
    const int deg   = cnt[node];
    const int w    = l & 15;       // dims 8w..8w+7 (head = w>>2)
    const int slot = l >> 4;       // edge slot 0..3

    const uint4 q = *(const uint4*)&Qh[(size_t)node * 128 + w * 8];
    float qf[8];
    { h16x2 t;
      t = u2h(q.x); qf[0] = (float)t.x; qf[1] = (float)t.y;
      t = u2h(q.y); qf[2] = (float)t.x; qf[3] = (float)t.y;
      t = u2h(q.z); qf[4] = (float)t.x; qf[5] = (float)t.y;
      t = u2h(q.w); qf[6] = (float)t.x; qf[7] = (float)t.y; }

    float of[8] = {0, 0, 0, 0, 0, 0, 0, 0};
    float denom = 0.f;

    for (int base = 0; base < deg; base += 64) {
        int m = deg - base; if (m > 64) m = 64;
        int myidx = 0;
        if (l < m) myidx = csrc[start + base + l];
        for (int j = 0; j < m; j += 4) {
            int eloc = j + slot;
            int s = __shfl(myidx, eloc & 63);
            const uint4 kv = *(const uint4*)&KVb[(size_t)s * 128 + w * 8];
            f32x2 k01 = unpk_fp8_lo(kv.x), k23 = unpk_fp8_hi(kv.x);
            f32x2 k45 = unpk_fp8_lo(kv.y), k67 = unpk_fp8_hi(kv.y);
            float p;
            p = qf[0] * k01.x;
            p = fmaf(qf[1], k01.y, p);
            p = fmaf(qf[2], k23.x, p);
            p = fmaf(qf[3], k23.y, p);
            p = fmaf(qf[4], k45.x, p);
            p = fmaf(qf[5], k45.y, p);
            p = fmaf(qf[6], k67.x, p);
            p = fmaf(qf[7], k67.y, p);
            p += __shfl_xor(p, 1);
            p += __shfl_xor(p, 2);
            float al = __expf(p * ATT_SCALE);
            al = (eloc < m) ? al : 0.f;
            denom += al;
            f32x2 v01 = unpk_fp8_lo(kv.z), v23 = unpk_fp8_hi(kv.z);
            f32x2 v45 = unpk_fp8_lo(kv.w), v67 = unpk_fp8_hi(kv.w);
            of[0] = fmaf(al, v01.x, of[0]);
            of[1] = fmaf(al, v01.y, of[1]);
            of[2] = fmaf(al, v23.x, of[2]);
            of[3] = fmaf(al, v23.y, of[3]);
            of[4] = fmaf(al, v45.x, of[4]);
            of[5] = fmaf(al, v45.y, of[5]);
            of[6] = fmaf(al, v67.x, of[6]);
            of[7] = fmaf(al, v67.y, of[7]);
        }
    }

    // cross-slot reduce (lanes l, l^16, l^32 hold same dims)
    #pragma unroll
    for (int msk = 16; msk <= 32; msk <<= 1) {
        #pragma unroll
        for (int i = 0; i < 8; ++i) of[i] += __shfl_xor(of[i], msk);
        denom += __shfl_xor(denom, msk);
    }
    float inv = (deg > 0) ? (1.f / denom) : 0.f;
    if (slot == 0) {
        u32 wrd[4];
        #pragma unroll
        for (int i = 0; i < 4; ++i)
            wrd[i] = (u32)f2b(of[2 * i] * inv) | ((u32)f2b(of[2 * i + 1] * inv) << 16);
        uint4 uu = make_uint4(wrd[0], wrd[1], wrd[2], wrd[3]);
        *(uint4*)&hnew[(size_t)node * 128 + w * 8] = uu;
    }
}

// ---------------------------------------------------------------------------
// Attn-out + residual + LN2: h1 fp32, h2 bf16.
// ---------------------------------------------------------------------------
__global__ __launch_bounds__(256) void k_attnout(
    const u16* __restrict__ hnew, const u16* __restrict__ Bo, const float* __restrict__ bo,
    const float* __restrict__ h, const float* __restrict__ g2, const float* __restrict__ be2,
    float* __restrict__ h1, u16* __restrict__ h2, int M)
{
    const int slab = blockIdx.x * 4 + (threadIdx.x >> 6);
    const int l = threadIdx.x & 63;
    const int r0 = slab * 16;
    if (r0 >= M) return;
    const int col = l & 15, hg = l >> 4;
    const u16* ar = hnew + (size_t)(r0 + col) * 128 + hg * 8;
    bf16x8 a0 = *(const bf16x8*)(ar);
    bf16x8 a1 = *(const bf16x8*)(ar + 32);
    bf16x8 a2 = *(const bf16x8*)(ar + 64);
    bf16x8 a3 = *(const bf16x8*)(ar + 96);
    f32x4 acc[8];
    #pragma unroll
    for (int t = 0; t < 8; ++t) {
        float bb = bo[t * 16 + col];
        f32x4 c = {bb, bb, bb, bb};
        const u16* bp = Bo + t * 2048 + l * 8;
        c = MFMA(a0, *(const bf16x8*)(bp),        c);
        c = MFMA(a1, *(const bf16x8*)(bp + 512),  c);
        c = MFMA(a2, *(const bf16x8*)(bp + 1024), c);
        c = MFMA(a3, *(const bf16x8*)(bp + 1536), c);
        acc[t] = c;
    }
    float s[4] = {0, 0, 0, 0}, s2[4] = {0, 0, 0, 0};
    #pragma unroll
    for (int t = 0; t < 8; ++t) {
        #pragma unroll
        for (int r = 0; r < 4; ++r) {
            float x = acc[t][r] + h[(size_t)(r0 + hg * 4 + r) * 128 + t * 16 + col];
            acc[t][r] = x;
            s[r] += x; s2[r] += x * x;
        }
    }
    float mean[4], rs[4];
    #pragma unroll
    for (int r = 0; r < 4; ++r) {
        float a = s[r], b = s2[r];
        a += __shfl_xor(a, 1); b += __shfl_xor(b, 1);
        a += __shfl_xor(a, 2); b += __shfl_xor(b, 2);
        a += __shfl_xor(a, 4); b += __shfl_xor(b, 4);
        a += __shfl_xor(a, 8); b += __shfl_xor(b, 8);
        mean[r] = a * (1.f / 128.f);
        float var = b * (1.f / 128.f) - mean[r] * mean[r];
        rs[r] = rsqrtf(var + EPS);
    }
    #pragma unroll
    for (int t = 0; t < 8; ++t) {
        float g  = g2[t * 16 + col];
        float be = be2[t * 16 + col];
        #pragma unroll
        for (int r = 0; r < 4; ++r) {
            size_t idx = (size_t)(r0 + hg * 4 + r) * 128 + t * 16 + col;
            float x = acc[t][r];
            h1[idx] = x;
            h2[idx] = f2b((x - mean[r]) * rs[r] * g + be);
        }
    }
}

// ---------------------------------------------------------------------------
// FFN fused: t = relu(h2 @ W1 + b1) kept in per-wave LDS tile [16][256] bf16;
// out = h1 + t @ W2 + b2.  Transpose logic identical to verified round-7 k_tail.
// ---------------------------------------------------------------------------
__global__ __launch_bounds__(256) void k_ffn(
    const u16* __restrict__ h2, const u16* __restrict__ B1, const float* __restrict__ b1,
    const u16* __restrict__ B2, const float* __restrict__ b2,
    const float* __restrict__ h1, float* __restrict__ out, int M)
{
    __shared__ u16 smem[4][4096];                 // 8 KB per wave: [16][256] bf16
    const int wid = threadIdx.x >> 6;
    const int l   = threadIdx.x & 63;
    int slab = blockIdx.x * 4 + wid;
    const bool valid = (slab * 16) < M;
    if (!valid) slab = 0;
    const int r0  = slab * 16;
    const int col = l & 15, hg = l >> 4;
    u16* ws = smem[wid];

    const u16* ar = h2 + (size_t)(r0 + col) * 128 + hg * 8;
    bf16x8 f1a = *(const bf16x8*)(ar);
    bf16x8 f1b = *(const bf16x8*)(ar + 32);
    bf16x8 f1c = *(const bf16x8*)(ar + 64);
    bf16x8 f1d = *(const bf16x8*)(ar + 96);

    // ---- FFN1 + ReLU -> LDS [16][256] swizzled ----
    #pragma unroll
    for (int t = 0; t < 16; ++t) {
        float bb = b1[t * 16 + col];
        f32x4 c = {bb, bb, bb, bb};
        const u16* bp = B1 + t * 2048 + l * 8;
        c = MFMA(f1a, *(const bf16x8*)(bp),        c);
        c = MFMA(f1b, *(const bf16x8*)(bp + 512),  c);
        c = MFMA(f1c, *(const bf16x8*)(bp + 1024), c);
        c = MFMA(f1d, *(const bf16x8*)(bp + 1536), c);
        #pragma unroll
        for (int r = 0; r < 4; ++r)
            ws[swz(hg * 4 + r, t * 16 + col, 256)] = f2b(fmaxf(c[r], 0.f));
    }
    __syncthreads();
    // ---- FFN2 A-frags from LDS ----
    bf16x8 f2[8];
    #pragma unroll
    for (int i = 0; i < 8; ++i)
        f2[i] = *(const bf16x8*)&ws[swz(col, i * 32 + hg * 8, 256)];
    // ---- FFN2 + h1 -> out (line-coalesced scalar stores) ----
    #pragma unroll
    for (int t = 0; t < 8; ++t) {
        float bb = b2[t * 16 + col];
        f32x4 c = {bb, bb, bb, bb};
        const u16* bp = B2 + t * 4096 + l * 8;
        #pragma unroll
        for (int kc = 0; kc < 8; ++kc)
            c = MFMA(f2[kc], *(const bf16x8*)(bp + kc * 512), c);
        if (valid) {
            #pragma unroll
            for (int r = 0; r < 4; ++r) {
                size_t idx = (size_t)(r0 + hg * 4 + r) * 128 + t * 16 + col;
                out[idx] = c[r] + h1[idx];
            }
        }
    }
}

// ---------------------------------------------------------------------------
extern "C" void kernel_launch(void* const* d_in, const int* in_sizes, int n_in,
                              void* d_out, int out_size, void* d_ws, size_t ws_size,
                              hipStream_t stream)
{
    const float* h   = (const float*)d_in[0];
    const int*   src = (const int*)  d_in[1];
    const int*   dst = (const int*)  d_in[2];
    const float* Wq  = (const float*)d_in[3];
    const float* bq  = (const float*)d_in[4];
    const float* Wk  = (const float*)d_in[5];
    const float* bk  = (const float*)d_in[6];
    const float* Wv  = (const float*)d_in[7];
    const float* bv  = (const float*)d_in[8];
    const float* Wo  = (const float*)d_in[9];
    const float* bo  = (const float*)d_in[10];
    const float* W1  = (const float*)d_in[11];
    const float* b1  = (const float*)d_in[12];
    const float* W2  = (const float*)d_in[13];
    const float* b2  = (const float*)d_in[14];
    const float* g1  = (const float*)d_in[15];
    const float* be1 = (const float*)d_in[16];
    const float* g2  = (const float*)d_in[17];
    const float* be2 = (const float*)d_in[18];

    const int n = in_sizes[0] / HIDN;    // 100000
    const int e = in_sizes[1];           // 1600000
    float* out = (float*)d_out;

    const int nbuck = (n + 255) >> BSH;

    // --- workspace layout ---
    char* p = (char*)d_ws;
    int* csrc  = (int*)p;              p += (size_t)e * 4;
    int* cnt   = (int*)p;              p += (size_t)n * 4;
    int* offs  = (int*)p;              p += (size_t)n * 4;
    int* bcnt  = (int*)p;              p += 512 * 4;
    int* bbase = (int*)p;              p += 512 * 4;
    int* bcur  = (int*)p;              p += 512 * 4;
    u16* wpack = (u16*)p;              p += 131072 * 2;          // 256 KB packed weights
    u16* KVb  = (u16*)p;               p += (size_t)n * 128 * 2; // 25.6 MB fp8-packed K|V
    u16* Qh   = (u16*)p;               p += (size_t)n * 128 * 2; // 25.6 MB Q fp16
    u16* hnew = (u16*)p;               p += (size_t)n * 128 * 2; // 25.6 MB bf16
    float* h1 = (float*)p;             p += (size_t)n * 128 * 4; // 51.2 MB fp32
    // aliases (lifetimes disjoint)
    u16* h2 = Qh;                      // Qh dead after k_edge
    u32* ebuf = (u32*)h1;              // ebuf dead after k_bbuild; h1 written later

    u16* Wq_p = wpack;
    u16* Wk_p = wpack + 16384;
    u16* Wv_p = wpack + 32768;
    u16* Wo_p = wpack + 49152;
    u16* W1_p = wpack + 65536;
    u16* W2_p = wpack + 98304;

    const int nslab = (n + 15) / 16;
    const int gemm_blocks = (nslab + 3) / 4;
    const int echunks = (e + CHUNK - 1) / CHUNK;

    hipMemsetAsync(bcnt, 0, 512 * sizeof(int), stream);

    k_bcount  <<<echunks, 256, 0, stream>>>(dst, bcnt, e);
    k_bscan   <<<1, 512, 0, stream>>>(bcnt, bbase, bcur, nbuck);
    k_bscatter<<<echunks, 256, 0, stream>>>(src, dst, bcur, ebuf, e);
    k_bbuild  <<<nbuck, 256, 0, stream>>>(ebuf, bbase, cnt, offs, csrc, n);

    k_pack_all<<<64, 256, 0, stream>>>(Wq, Wk, Wv, Wo, W1, W2, wpack);

    k_qkv <<<gemm_blocks, 256, 0, stream>>>(h, g1, be1, Wq_p, Wk_p, Wv_p,
                                            bq, bk, bv, Qh, KVb, n);

    k_edge<<<(n + 3) / 4, 256, 0, stream>>>(Qh, KVb, offs, cnt, csrc, hnew, n);

    k_attnout<<<gemm_blocks, 256, 0, stream>>>(hnew, Wo_p, bo, h, g2, be2, h1, h2, n);

    k_ffn <<<gemm_blocks, 256, 0, stream>>>(h2, W1_p, b1, W2_p, b2, h1, out, n);
}